// Round 5
// baseline (1184.859 us; speedup 1.0000x reference)
//
#include <hip/hip_runtime.h>
#include <math.h>

// Problem constants (fixed by reference)
#define B_    16
#define NP_   1024
#define FEAT_ 512
#define H_    1024
#define E_    262144          // B*NP*DEG
#define K1_   820             // ceil(0.8*1024)
#define K2_   656             // ceil(0.8*820)
#define K3_   525             // ceil(0.8*656)
#define M1_   16384           // B*NP
#define M2_   13120           // B*K1
#define M3_   10496           // B*K2
#define MP1_  16384           // padded to x128
#define MP2_  13184
#define MP3_  10496

typedef unsigned short ushort_t;
typedef __bf16 bf16x8 __attribute__((ext_vector_type(8)));
typedef float f32x4 __attribute__((ext_vector_type(4)));

// ---- bf16 split helpers (RNE) ----
__device__ inline ushort_t f2bf(float f) {
    unsigned u = __float_as_uint(f);
    u += 0x7FFF + ((u >> 16) & 1);
    return (ushort_t)(u >> 16);
}
__device__ inline float bf2f(ushort_t h) {
    return __uint_as_float(((unsigned)h) << 16);
}
__device__ inline void split1(float v, ushort_t& hi, ushort_t& lo) {
    hi = f2bf(v);
    lo = f2bf(v - bf2f(hi));
}

__device__ inline void gll16(const void* g, void* l) {
    __builtin_amdgcn_global_load_lds((__attribute__((address_space(1))) void*)g,
                                     (__attribute__((address_space(3))) void*)l, 16, 0, 0);
}

// ---------------- edge bookkeeping ----------------

__global__ void init_edges_count(const int* __restrict__ ei, int* __restrict__ esrc,
                                 int* __restrict__ edst, int* __restrict__ emask,
                                 int* __restrict__ counts) {
    int e = blockIdx.x * 256 + threadIdx.x;
    int s = ei[e], d = ei[E_ + e];
    esrc[e] = s;
    edst[e] = d;
    emask[e] = 1;
    atomicAdd(&counts[d], 1);
}

// single-block scan: 1024 threads x 16 items serial + one block-scan of partials
__global__ __launch_bounds__(1024) void scan16_kernel(const int* __restrict__ counts,
                                                      int* __restrict__ offsets,
                                                      int* __restrict__ cursor, int M) {
    __shared__ int part[1024];
    int t = threadIdx.x;
    int base = t * 16;
    int v[16];
    int s = 0;
#pragma unroll
    for (int i = 0; i < 16; ++i) {
        int idx = base + i;
        v[i] = s;
        int c = (idx < M) ? counts[idx] : 0;
        s += c;
    }
    part[t] = s;
    __syncthreads();
    for (int off = 1; off < 1024; off <<= 1) {
        int tv = (t >= off) ? part[t - off] : 0;
        __syncthreads();
        part[t] += tv;
        __syncthreads();
    }
    int excl = part[t] - s;
#pragma unroll
    for (int i = 0; i < 16; ++i) {
        int idx = base + i;
        if (idx < M) {
            int o = excl + v[i];
            offsets[idx] = o;
            cursor[idx] = o;
        }
    }
}

__global__ void fill_kernel(const int* __restrict__ esrc, const int* __restrict__ edst,
                            const int* __restrict__ emask, int* __restrict__ cursor,
                            int* __restrict__ adj) {
    int e = blockIdx.x * 256 + threadIdx.x;
    if (emask[e]) {
        int pos = atomicAdd(&cursor[edst[e]], 1);
        adj[pos] = esrc[e];
    }
}

// remap edges to pooled ids AND count next-layer in-degrees (counts pre-zeroed by topk)
__global__ void edge_update_count(int* __restrict__ esrc, int* __restrict__ edst,
                                  int* __restrict__ emask, const int* __restrict__ remap,
                                  int* __restrict__ counts) {
    int e = blockIdx.x * 256 + threadIdx.x;
    if (emask[e]) {
        int ns = remap[esrc[e]];
        int nd = remap[edst[e]];
        if (ns >= 0 && nd >= 0) {
            esrc[e] = ns; edst[e] = nd;
            atomicAdd(&counts[nd], 1);
        } else { esrc[e] = 0; edst[e] = 0; emask[e] = 0; }
    } else {
        esrc[e] = 0; edst[e] = 0;
    }
}

// ---------------- fused aggregation + pack, float4 gather, XCD-swizzled ----------------
// Abig row layout (4K cols, bf16): [agg_hi(K) | agg_lo(K) | cur_hi(K) | cur_lo(K)]

// K=1024: 1 node/block, 256 threads = 256 float4 cols.
__global__ __launch_bounds__(256) void agg_pack_k1024(const float* __restrict__ x,
                                                      const int* __restrict__ adj,
                                                      const int* __restrict__ offsets,
                                                      const int* __restrict__ counts,
                                                      ushort_t* __restrict__ Abig,
                                                      int n_per) {
    int b = blockIdx.x;
    int q = b >> 3;
    int over = (q >= n_per) ? 1 : 0;
    int g = (b & 7) + over * 8;
    int node = g * n_per + (q - over * n_per);
    int start = offsets[node], cnt = counts[node];
    float d = fmaxf((float)cnt, 1.0f);
    int c = threadIdx.x;
    const float4* xb = (const float4*)x + c;
    float ax = 0.f, ay = 0.f, az = 0.f, aw = 0.f;
    int j = 0;
    for (; j + 4 <= cnt; j += 4) {
        int s0 = adj[start + j + 0];
        int s1 = adj[start + j + 1];
        int s2 = adj[start + j + 2];
        int s3 = adj[start + j + 3];
        float4 v0 = xb[(size_t)s0 * 256];
        float4 v1 = xb[(size_t)s1 * 256];
        float4 v2 = xb[(size_t)s2 * 256];
        float4 v3 = xb[(size_t)s3 * 256];
        ax += (v0.x + v1.x) + (v2.x + v3.x);
        ay += (v0.y + v1.y) + (v2.y + v3.y);
        az += (v0.z + v1.z) + (v2.z + v3.z);
        aw += (v0.w + v1.w) + (v2.w + v3.w);
    }
    for (; j < cnt; ++j) {
        float4 v = xb[(size_t)adj[start + j] * 256];
        ax += v.x; ay += v.y; az += v.z; aw += v.w;
    }
    float inv = 1.0f / d;
    float4 cv = xb[(size_t)node * 256];
    ushort_t* row = Abig + (size_t)node * 4096;
    ushort4 mh, ml, ch, cl;
    split1(ax * inv, mh.x, ml.x); split1(ay * inv, mh.y, ml.y);
    split1(az * inv, mh.z, ml.z); split1(aw * inv, mh.w, ml.w);
    split1(cv.x, ch.x, cl.x); split1(cv.y, ch.y, cl.y);
    split1(cv.z, ch.z, cl.z); split1(cv.w, ch.w, cl.w);
    *(ushort4*)&row[c * 4]        = mh;
    *(ushort4*)&row[1024 + c * 4] = ml;
    *(ushort4*)&row[2048 + c * 4] = ch;
    *(ushort4*)&row[3072 + c * 4] = cl;
}

// K=512: 2 nodes/block. blocks = 8192.
__global__ __launch_bounds__(256) void agg_pack_k512(const float* __restrict__ x,
                                                     const int* __restrict__ adj,
                                                     const int* __restrict__ offsets,
                                                     const int* __restrict__ counts,
                                                     ushort_t* __restrict__ Abig) {
    int b = blockIdx.x;
    int q = b >> 3;
    int over = (q >= 512) ? 1 : 0;
    int g = (b & 7) + over * 8;
    int node = g * 1024 + (q - over * 512) * 2 + (threadIdx.x >> 7);
    int start = offsets[node], cnt = counts[node];
    float d = fmaxf((float)cnt, 1.0f);
    int c = threadIdx.x & 127;
    const float4* xb = (const float4*)x + c;
    float ax = 0.f, ay = 0.f, az = 0.f, aw = 0.f;
    int j = 0;
    for (; j + 4 <= cnt; j += 4) {
        int s0 = adj[start + j + 0];
        int s1 = adj[start + j + 1];
        int s2 = adj[start + j + 2];
        int s3 = adj[start + j + 3];
        float4 v0 = xb[(size_t)s0 * 128];
        float4 v1 = xb[(size_t)s1 * 128];
        float4 v2 = xb[(size_t)s2 * 128];
        float4 v3 = xb[(size_t)s3 * 128];
        ax += (v0.x + v1.x) + (v2.x + v3.x);
        ay += (v0.y + v1.y) + (v2.y + v3.y);
        az += (v0.z + v1.z) + (v2.z + v3.z);
        aw += (v0.w + v1.w) + (v2.w + v3.w);
    }
    for (; j < cnt; ++j) {
        float4 v = xb[(size_t)adj[start + j] * 128];
        ax += v.x; ay += v.y; az += v.z; aw += v.w;
    }
    float inv = 1.0f / d;
    float4 cv = xb[(size_t)node * 128];
    ushort_t* row = Abig + (size_t)node * 2048;
    ushort4 mh, ml, ch, cl;
    split1(ax * inv, mh.x, ml.x); split1(ay * inv, mh.y, ml.y);
    split1(az * inv, mh.z, ml.z); split1(aw * inv, mh.w, ml.w);
    split1(cv.x, ch.x, cl.x); split1(cv.y, ch.y, cl.y);
    split1(cv.z, ch.z, cl.z); split1(cv.w, ch.w, cl.w);
    *(ushort4*)&row[c * 4]        = mh;
    *(ushort4*)&row[512 + c * 4]  = ml;
    *(ushort4*)&row[1024 + c * 4] = ch;
    *(ushort4*)&row[1536 + c * 4] = cl;
}

__global__ __launch_bounds__(256) void pack_w_kernel(const float* __restrict__ Wl,
                                                     const float* __restrict__ Wr,
                                                     ushort_t* __restrict__ Wbig, int K) {
    int idx = blockIdx.x * 256 + threadIdx.x;
    int n = idx / K;
    int k = idx - n * K;
    ushort_t* row = Wbig + (size_t)n * (4 * K);
    float a = Wl[idx];
    ushort_t ah = f2bf(a);
    row[k] = ah;
    row[K + k] = f2bf(a - bf2f(ah));
    float b = Wr[idx];
    ushort_t bh = f2bf(b);
    row[2 * K + k] = bh;
    row[3 * K + k] = f2bf(b - bf2f(bh));
}

// ---------------- MFMA GEMM + fused raw-score epilogue ----------------
// grid = (8, Mp/128) (R3 order: consecutive blocks = col-blocks of one row-panel).
// Epilogue: h=relu(acc+bias) store + per-block partial dot(h, p) -> atomicAdd raw scores.

__global__ __launch_bounds__(256) void gemm_mfma(const ushort_t* __restrict__ Ab,
                                                 const ushort_t* __restrict__ Wb,
                                                 const float* __restrict__ bias,
                                                 float* __restrict__ C,
                                                 float* __restrict__ scoresRaw,
                                                 const float* __restrict__ pvec,
                                                 int K) {
    __shared__ ushort_t lA0[4096];
    __shared__ ushort_t lA1[4096];
    __shared__ ushort_t lB0[4096];
    __shared__ ushort_t lB1[4096];
    const int LD = 4 * K;
    int tid = threadIdx.x;
    int lane = tid & 63;
    int w = tid >> 6;
    int wr = (w >> 1) * 64, wc = (w & 1) * 64;
    int m0 = blockIdx.y * 128, n0 = blockIdx.x * 128;

    int srow = tid >> 2;
    int gq = (tid & 3) ^ ((tid >> 2) & 3) ^ ((tid >> 4) & 3);
    const ushort_t* Ag = Ab + (size_t)(m0 + srow) * LD + gq * 8;
    const ushort_t* Bg = Wb + (size_t)(n0 + srow) * LD + gq * 8;
    ushort_t* lA0p = &lA0[tid * 8];
    ushort_t* lA1p = &lA1[tid * 8];
    ushort_t* lB0p = &lB0[tid * 8];
    ushort_t* lB1p = &lB1[tid * 8];
    const size_t rstep = (size_t)64 * LD;

    int qsw = (lane >> 4) ^ (lane & 3) ^ ((lane >> 2) & 3);
    int aidx = (wr + (lane & 15)) * 32 + qsw * 8;
    int bidx = (wc + (lane & 15)) * 32 + qsw * 8;

    f32x4 acc[4][4];
#pragma unroll
    for (int i = 0; i < 4; ++i)
#pragma unroll
        for (int j = 0; j < 4; ++j) acc[i][j] = (f32x4){0.f, 0.f, 0.f, 0.f};

    for (int ss = 0; ss < 2; ++ss) {
        const ushort_t* Ah = Ag + ss * 2 * K;
        const ushort_t* Bh = Bg + ss * 2 * K;
        for (int kk = 0; kk < K; kk += 32) {
            __syncthreads();
            gll16(Ah + kk, lA0p);
            gll16(Ah + kk + rstep, lA0p + 2048);
            gll16(Ah + K + kk, lA1p);
            gll16(Ah + K + kk + rstep, lA1p + 2048);
            gll16(Bh + kk, lB0p);
            gll16(Bh + kk + rstep, lB0p + 2048);
            gll16(Bh + K + kk, lB1p);
            gll16(Bh + K + kk + rstep, lB1p + 2048);
            __syncthreads();
            bf16x8 a0[4], a1[4], b0[4], b1[4];
#pragma unroll
            for (int i = 0; i < 4; ++i) a0[i] = *(const bf16x8*)&lA0[aidx + i * 512];
#pragma unroll
            for (int j = 0; j < 4; ++j) b0[j] = *(const bf16x8*)&lB0[bidx + j * 512];
#pragma unroll
            for (int i = 0; i < 4; ++i)
#pragma unroll
                for (int j = 0; j < 4; ++j)
                    acc[i][j] = __builtin_amdgcn_mfma_f32_16x16x32_bf16(a0[i], b0[j], acc[i][j], 0, 0, 0);
#pragma unroll
            for (int i = 0; i < 4; ++i) a1[i] = *(const bf16x8*)&lA1[aidx + i * 512];
#pragma unroll
            for (int i = 0; i < 4; ++i)
#pragma unroll
                for (int j = 0; j < 4; ++j)
                    acc[i][j] = __builtin_amdgcn_mfma_f32_16x16x32_bf16(a1[i], b0[j], acc[i][j], 0, 0, 0);
#pragma unroll
            for (int j = 0; j < 4; ++j) b1[j] = *(const bf16x8*)&lB1[bidx + j * 512];
#pragma unroll
            for (int i = 0; i < 4; ++i)
#pragma unroll
                for (int j = 0; j < 4; ++j)
                    acc[i][j] = __builtin_amdgcn_mfma_f32_16x16x32_bf16(a0[i], b1[j], acc[i][j], 0, 0, 0);
        }
    }

    float bj[4], pj[4];
#pragma unroll
    for (int j = 0; j < 4; ++j) {
        int col = n0 + wc + j * 16 + (lane & 15);
        bj[j] = bias[col];
        pj[j] = pvec[col];
    }
#pragma unroll
    for (int i = 0; i < 4; ++i) {
        int row0 = m0 + wr + i * 16 + (lane >> 4) * 4;
        float sacc[4] = {0.f, 0.f, 0.f, 0.f};
#pragma unroll
        for (int j = 0; j < 4; ++j) {
            int col = n0 + wc + j * 16 + (lane & 15);
#pragma unroll
            for (int r = 0; r < 4; ++r) {
                float v = acc[i][j][r] + bj[j];
                v = v > 0.f ? v : 0.f;
                C[(size_t)(row0 + r) * 1024 + col] = v;
                sacc[r] += v * pj[j];
            }
        }
#pragma unroll
        for (int r = 0; r < 4; ++r) {
            float sv_ = sacc[r];
            sv_ += __shfl_xor(sv_, 1);
            sv_ += __shfl_xor(sv_, 2);
            sv_ += __shfl_xor(sv_, 4);
            sv_ += __shfl_xor(sv_, 8);
            if ((lane & 15) == 0) atomicAdd(&scoresRaw[row0 + r], sv_);
        }
    }
}

// ---------------- scoring norms + top-k by rank ----------------

__global__ __launch_bounds__(256) void pnorm3_kernel(const float* __restrict__ p1,
                                                     const float* __restrict__ p2,
                                                     const float* __restrict__ p3,
                                                     float* __restrict__ out) {
    const float* p = blockIdx.x == 0 ? p1 : (blockIdx.x == 1 ? p2 : p3);
    __shared__ float red[256];
    float a = 0.f;
    for (int i = threadIdx.x; i < 1024; i += 256) { float v = p[i]; a += v * v; }
    red[threadIdx.x] = a;
    __syncthreads();
    for (int s = 128; s > 0; s >>= 1) {
        if (threadIdx.x < s) red[threadIdx.x] += red[threadIdx.x + s];
        __syncthreads();
    }
    if (threadIdx.x == 0) out[blockIdx.x] = sqrtf(red[0]);
}

// one block per graph; rank = #{j: s_j > s_i or (s_j==s_i and j<i)}; keep rank<k.
// Matches stable descending top_k: pos = rank. Also zeros next-layer counts.
__global__ __launch_bounds__(1024) void topk_rank(const float* __restrict__ s, int n, int k,
                                                  const float* __restrict__ pn,
                                                  int* __restrict__ old_idx, float* __restrict__ vals,
                                                  int* __restrict__ remap, int* __restrict__ counts) {
    __shared__ float sv[1024];
    int b = blockIdx.x, t = threadIdx.x;
    float mine = (t < n) ? s[b * n + t] : -INFINITY;
    sv[t] = mine;
    if (t < n) remap[b * n + t] = -1;
    __syncthreads();
    int rank = 0;
#pragma unroll 4
    for (int j = 0; j < 1024; ++j) {
        float o = sv[j];
        rank += (o > mine) || (o == mine && j < t);
    }
    if (t < n && rank < k) {
        int old = b * n + t;
        int pos = b * k + rank;
        old_idx[pos] = old;
        vals[pos] = tanhf(mine / pn[0]);
        remap[old] = pos;
    }
    if (t < k) counts[b * k + t] = 0;
}

__global__ __launch_bounds__(256) void compact_kernel(const float* __restrict__ h,
                                                      const int* __restrict__ old_idx,
                                                      const float* __restrict__ vals,
                                                      float* __restrict__ xn) {
    int j = blockIdx.x;
    int o = old_idx[j];
    float v = vals[j];
    const float4* src = (const float4*)(h + (size_t)o * 1024);
    float4* dst = (float4*)(xn + (size_t)j * 1024);
    float4 t = src[threadIdx.x];
    t.x *= v; t.y *= v; t.z *= v; t.w *= v;
    dst[threadIdx.x] = t;
}

__global__ __launch_bounds__(256) void readout_kernel(const float* __restrict__ xn, int k,
                                                      float* __restrict__ out) {
    int b = blockIdx.x;
    int c = threadIdx.x;
    const float4* base = (const float4*)xn + (size_t)b * k * 256 + c;
    float4 mx = {-INFINITY, -INFINITY, -INFINITY, -INFINITY};
    float4 sm = {0.f, 0.f, 0.f, 0.f};
    int i = 0;
    for (; i + 4 <= k; i += 4) {
        float4 v0 = base[(size_t)(i + 0) * 256];
        float4 v1 = base[(size_t)(i + 1) * 256];
        float4 v2 = base[(size_t)(i + 2) * 256];
        float4 v3 = base[(size_t)(i + 3) * 256];
        mx.x = fmaxf(fmaxf(fmaxf(mx.x, v0.x), fmaxf(v1.x, v2.x)), v3.x);
        mx.y = fmaxf(fmaxf(fmaxf(mx.y, v0.y), fmaxf(v1.y, v2.y)), v3.y);
        mx.z = fmaxf(fmaxf(fmaxf(mx.z, v0.z), fmaxf(v1.z, v2.z)), v3.z);
        mx.w = fmaxf(fmaxf(fmaxf(mx.w, v0.w), fmaxf(v1.w, v2.w)), v3.w);
        sm.x += (v0.x + v1.x) + (v2.x + v3.x);
        sm.y += (v0.y + v1.y) + (v2.y + v3.y);
        sm.z += (v0.z + v1.z) + (v2.z + v3.z);
        sm.w += (v0.w + v1.w) + (v2.w + v3.w);
    }
    for (; i < k; ++i) {
        float4 v = base[(size_t)i * 256];
        mx.x = fmaxf(mx.x, v.x); mx.y = fmaxf(mx.y, v.y);
        mx.z = fmaxf(mx.z, v.z); mx.w = fmaxf(mx.w, v.w);
        sm.x += v.x; sm.y += v.y; sm.z += v.z; sm.w += v.w;
    }
    float invk = 1.0f / (float)k;
    float* o0 = out + (size_t)b * 2048 + c * 4;
    o0[0] += mx.x; o0[1] += mx.y; o0[2] += mx.z; o0[3] += mx.w;
    float* o1 = o0 + 1024;
    o1[0] += sm.x * invk; o1[1] += sm.y * invk; o1[2] += sm.z * invk; o1[3] += sm.w * invk;
}

// ---------------- host-side layer driver ----------------

static void run_layer(const float* cur, int K, int M, int Mp, int n_per, int k_keep,
                      const float* Wl, const float* bias, const float* Wr,
                      const float* p, const float* pn, bool last,
                      ushort_t* Abig, ushort_t* Wbig, float* bufOut, float* bufNext,
                      int* esrc, int* edst, int* emask,
                      int* counts, int* offsets, int* cursor, int* adj,
                      float* scoresRaw, int* old_idx, float* vals, int* remap,
                      float* out, hipStream_t stream) {
    scan16_kernel<<<1, 1024, 0, stream>>>(counts, offsets, cursor, M);
    fill_kernel<<<E_ / 256, 256, 0, stream>>>(esrc, edst, emask, cursor, adj);
    if (Mp > M)
        hipMemsetAsync(Abig + (size_t)M * 4 * K, 0, (size_t)(Mp - M) * 4 * K * 2, stream);
    if (K == 512)
        agg_pack_k512<<<8192, 256, 0, stream>>>(cur, adj, offsets, counts, Abig);
    else
        agg_pack_k1024<<<M, 256, 0, stream>>>(cur, adj, offsets, counts, Abig, n_per);
    pack_w_kernel<<<(1024 * K) / 256, 256, 0, stream>>>(Wl, Wr, Wbig, K);
    gemm_mfma<<<dim3(8, Mp / 128), 256, 0, stream>>>(Abig, Wbig, bias, bufOut, scoresRaw, p, K);
    topk_rank<<<B_, 1024, 0, stream>>>(scoresRaw, n_per, k_keep, pn, old_idx, vals, remap, counts);
    if (!last) {
        hipMemsetAsync(scoresRaw, 0, 65536, stream);
        edge_update_count<<<E_ / 256, 256, 0, stream>>>(esrc, edst, emask, remap, counts);
    }
    compact_kernel<<<B_ * k_keep, 256, 0, stream>>>(bufOut, old_idx, vals, bufNext);
    readout_kernel<<<B_, 256, 0, stream>>>(bufNext, k_keep, out);
}

extern "C" void kernel_launch(void* const* d_in, const int* in_sizes, int n_in,
                              void* d_out, int out_size, void* d_ws, size_t ws_size,
                              hipStream_t stream) {
    const float* x   = (const float*)d_in[0];
    const int*   ei  = (const int*)d_in[1];
    const float* W1l = (const float*)d_in[3];
    const float* b1  = (const float*)d_in[4];
    const float* W1r = (const float*)d_in[5];
    const float* p1  = (const float*)d_in[6];
    const float* W2l = (const float*)d_in[7];
    const float* b2  = (const float*)d_in[8];
    const float* W2r = (const float*)d_in[9];
    const float* p2  = (const float*)d_in[10];
    const float* W3l = (const float*)d_in[11];
    const float* b3  = (const float*)d_in[12];
    const float* W3r = (const float*)d_in[13];
    const float* p3  = (const float*)d_in[14];
    float* out = (float*)d_out;

    char* ws = (char*)d_ws;
    size_t off = 0;
    float* bufOut = (float*)(ws + off); off += (size_t)MP1_ * 1024 * 4;            // 64 MB
    float* bufCur = (float*)(ws + off); off += (size_t)M2_ * 1024 * 4;             // 51.3 MB
    ushort_t* Abig = (ushort_t*)(ws + off); off += (size_t)MP2_ * 4096 * 2;        // 103 MB
    ushort_t* Wbig = (ushort_t*)(ws + off); off += (size_t)1024 * 4096 * 2;        // 8 MB
    char* misc = ws + off;
    float* scoresRaw = (float*)(misc + 0 * 65536);
    int*   counts = (int*)(misc + 1 * 65536);
    int*   offsets= (int*)(misc + 2 * 65536);
    int*   cursor = (int*)(misc + 3 * 65536);
    int*   old_idx= (int*)(misc + 4 * 65536);
    float* vals   = (float*)(misc + 5 * 65536);
    int*   remap  = (int*)(misc + 6 * 65536);
    float* pnormv = (float*)(misc + 7 * 65536);
    int*   adj    = (int*)(misc + 8 * 65536);
    int*   esrc   = (int*)(misc + 8 * 65536 + 1 * 1048576);
    int*   edst   = (int*)(misc + 8 * 65536 + 2 * 1048576);
    int*   emask  = (int*)(misc + 8 * 65536 + 3 * 1048576);

    hipMemsetAsync(d_out, 0, (size_t)out_size * sizeof(float), stream);
    hipMemsetAsync(counts, 0, 65536, stream);
    hipMemsetAsync(scoresRaw, 0, 65536, stream);
    pnorm3_kernel<<<3, 256, 0, stream>>>(p1, p2, p3, pnormv);
    init_edges_count<<<E_ / 256, 256, 0, stream>>>(ei, esrc, edst, emask, counts);

    // layer 1: cur = x (K=512), M=16384, pool 1024->820
    run_layer(x, FEAT_, M1_, MP1_, NP_, K1_, W1l, b1, W1r, p1, pnormv + 0, false,
              Abig, Wbig, bufOut, bufCur, esrc, edst, emask,
              counts, offsets, cursor, adj, scoresRaw, old_idx, vals, remap,
              out, stream);
    // layer 2: cur = pooled (K=1024), M=13120, pool 820->656
    run_layer(bufCur, H_, M2_, MP2_, K1_, K2_, W2l, b2, W2r, p2, pnormv + 1, false,
              Abig, Wbig, bufOut, bufCur, esrc, edst, emask,
              counts, offsets, cursor, adj, scoresRaw, old_idx, vals, remap,
              out, stream);
    // layer 3: cur = pooled (K=1024), M=10496, pool 656->525
    run_layer(bufCur, H_, M3_, MP3_, K2_, K3_, W3l, b3, W3r, p3, pnormv + 2, true,
              Abig, Wbig, bufOut, bufCur, esrc, edst, emask,
              counts, offsets, cursor, adj, scoresRaw, old_idx, vals, remap,
              out, stream);
}

// Round 6
// 1148.368 us; speedup vs baseline: 1.0318x; 1.0318x over previous
//
#include <hip/hip_runtime.h>
#include <math.h>

// Problem constants (fixed by reference)
#define B_    16
#define NP_   1024
#define FEAT_ 512
#define H_    1024
#define E_    262144          // B*NP*DEG
#define K1_   820             // ceil(0.8*1024)
#define K2_   656             // ceil(0.8*820)
#define K3_   525             // ceil(0.8*656)
#define M1_   16384           // B*NP
#define M2_   13120           // B*K1
#define M3_   10496           // B*K2
// padded row counts: panels (Mp/128) must be divisible by 8 for XCD-local mapping
#define MP1_  16384           // 128 panels
#define MP2_  13312           // 104 panels
#define MP3_  11264           // 88 panels
#define SPROWS_ 16384         // scoresPart row stride

typedef unsigned short ushort_t;
typedef __bf16 bf16x8 __attribute__((ext_vector_type(8)));
typedef float f32x4 __attribute__((ext_vector_type(4)));

// ---- bf16 split helpers (RNE) ----
__device__ inline ushort_t f2bf(float f) {
    unsigned u = __float_as_uint(f);
    u += 0x7FFF + ((u >> 16) & 1);
    return (ushort_t)(u >> 16);
}
__device__ inline float bf2f(ushort_t h) {
    return __uint_as_float(((unsigned)h) << 16);
}
__device__ inline void split1(float v, ushort_t& hi, ushort_t& lo) {
    hi = f2bf(v);
    lo = f2bf(v - bf2f(hi));
}

__device__ inline void gll16(const void* g, void* l) {
    __builtin_amdgcn_global_load_lds((__attribute__((address_space(1))) void*)g,
                                     (__attribute__((address_space(3))) void*)l, 16, 0, 0);
}

// ---------------- edge bookkeeping ----------------

__global__ void init_edges_count(const int* __restrict__ ei, int* __restrict__ esrc,
                                 int* __restrict__ edst, int* __restrict__ emask,
                                 int* __restrict__ counts) {
    int e = blockIdx.x * 256 + threadIdx.x;
    int s = ei[e], d = ei[E_ + e];
    esrc[e] = s;
    edst[e] = d;
    emask[e] = 1;
    atomicAdd(&counts[d], 1);
}

// single-block scan: 1024 threads x 16 items serial + one block-scan of partials
__global__ __launch_bounds__(1024) void scan16_kernel(const int* __restrict__ counts,
                                                      int* __restrict__ offsets,
                                                      int* __restrict__ cursor, int M) {
    __shared__ int part[1024];
    int t = threadIdx.x;
    int base = t * 16;
    int v[16];
    int s = 0;
#pragma unroll
    for (int i = 0; i < 16; ++i) {
        int idx = base + i;
        v[i] = s;
        int c = (idx < M) ? counts[idx] : 0;
        s += c;
    }
    part[t] = s;
    __syncthreads();
    for (int off = 1; off < 1024; off <<= 1) {
        int tv = (t >= off) ? part[t - off] : 0;
        __syncthreads();
        part[t] += tv;
        __syncthreads();
    }
    int excl = part[t] - s;
#pragma unroll
    for (int i = 0; i < 16; ++i) {
        int idx = base + i;
        if (idx < M) {
            int o = excl + v[i];
            offsets[idx] = o;
            cursor[idx] = o;
        }
    }
}

__global__ void fill_kernel(const int* __restrict__ esrc, const int* __restrict__ edst,
                            const int* __restrict__ emask, int* __restrict__ cursor,
                            int* __restrict__ adj) {
    int e = blockIdx.x * 256 + threadIdx.x;
    if (emask[e]) {
        int pos = atomicAdd(&cursor[edst[e]], 1);
        adj[pos] = esrc[e];
    }
}

// remap edges to pooled ids AND count next-layer in-degrees (counts pre-zeroed by topk)
__global__ void edge_update_count(int* __restrict__ esrc, int* __restrict__ edst,
                                  int* __restrict__ emask, const int* __restrict__ remap,
                                  int* __restrict__ counts) {
    int e = blockIdx.x * 256 + threadIdx.x;
    if (emask[e]) {
        int ns = remap[esrc[e]];
        int nd = remap[edst[e]];
        if (ns >= 0 && nd >= 0) {
            esrc[e] = ns; edst[e] = nd;
            atomicAdd(&counts[nd], 1);
        } else { esrc[e] = 0; edst[e] = 0; emask[e] = 0; }
    } else {
        esrc[e] = 0; edst[e] = 0;
    }
}

// ---------------- aggregation + pack (col-split halves, XCD-pinned) ----------------
// Abig row (4K cols bf16): [agg_hi(K) | agg_lo(K) | cur_hi(K) | cur_lo(K)]

// Layer 1: source = x (K=512), no gating. 128 thr: 2 nodes x 64 float4 cols (one half).
// Per-XCD working set: 2 graphs x 1024 rows x 1KB = 2MB (L2-resident).
__global__ __launch_bounds__(128) void agg1_k512(const float* __restrict__ x,
                                                 const int* __restrict__ adj,
                                                 const int* __restrict__ offsets,
                                                 const int* __restrict__ counts,
                                                 ushort_t* __restrict__ Abig) {
    int gid = blockIdx.x;
    int xcd = gid & 7;
    int u = gid >> 3;                    // [0, 2048)
    int half = u & 1;
    int pi = u >> 1;                     // [0, 1024)
    int gsel = (pi >= 512) ? 1 : 0;
    int g = xcd + (gsel << 3);
    int node = g * 1024 + (pi - (gsel << 9)) * 2 + (threadIdx.x >> 6);
    int c = threadIdx.x & 63;
    int col4 = half * 64 + c;            // [0,128) float4 col
    int start = offsets[node], cnt = counts[node];
    float d = fmaxf((float)cnt, 1.0f);
    const float4* xb = (const float4*)x;
    float ax = 0.f, ay = 0.f, az = 0.f, aw = 0.f;
    int j = 0;
    for (; j + 4 <= cnt; j += 4) {
        int s0 = adj[start + j + 0];
        int s1 = adj[start + j + 1];
        int s2 = adj[start + j + 2];
        int s3 = adj[start + j + 3];
        float4 v0 = xb[(size_t)s0 * 128 + col4];
        float4 v1 = xb[(size_t)s1 * 128 + col4];
        float4 v2 = xb[(size_t)s2 * 128 + col4];
        float4 v3 = xb[(size_t)s3 * 128 + col4];
        ax += (v0.x + v1.x) + (v2.x + v3.x);
        ay += (v0.y + v1.y) + (v2.y + v3.y);
        az += (v0.z + v1.z) + (v2.z + v3.z);
        aw += (v0.w + v1.w) + (v2.w + v3.w);
    }
    for (; j < cnt; ++j) {
        float4 v = xb[(size_t)adj[start + j] * 128 + col4];
        ax += v.x; ay += v.y; az += v.z; aw += v.w;
    }
    float inv = 1.0f / d;
    float4 cv = xb[(size_t)node * 128 + col4];
    ushort_t* row = Abig + (size_t)node * 2048;
    int f = col4 * 4;
    ushort4 mh, ml, ch, cl;
    split1(ax * inv, mh.x, ml.x); split1(ay * inv, mh.y, ml.y);
    split1(az * inv, mh.z, ml.z); split1(aw * inv, mh.w, ml.w);
    split1(cv.x, ch.x, cl.x); split1(cv.y, ch.y, cl.y);
    split1(cv.z, ch.z, cl.z); split1(cv.w, ch.w, cl.w);
    *(ushort4*)&row[f]        = mh;
    *(ushort4*)&row[512 + f]  = ml;
    *(ushort4*)&row[1024 + f] = ch;
    *(ushort4*)&row[1536 + f] = cl;
}

// Layers 2/3: source = gated prev-layer h via (old_idx, vals). K=1024.
// 128 thr = 1 node x 128 float4 cols (one half). grid = 32*n_per.
// Per-XCD working set: 2 graphs x n_per rows x 2KB <= 3.3MB (L2-resident).
__global__ __launch_bounds__(128) void agg23_k1024(const float* __restrict__ h,
                                                   const int* __restrict__ adj,
                                                   const int* __restrict__ offsets,
                                                   const int* __restrict__ counts,
                                                   const int* __restrict__ old_idx,
                                                   const float* __restrict__ vals,
                                                   ushort_t* __restrict__ Abig,
                                                   int n_per) {
    int gid = blockIdx.x;
    int xcd = gid & 7;
    int u = gid >> 3;                    // [0, 4*n_per)
    int half = u & 1;
    int nl = u >> 1;                     // [0, 2*n_per)
    int gsel = (nl >= n_per) ? 1 : 0;
    int g = xcd + (gsel << 3);
    int node = g * n_per + nl - gsel * n_per;
    int c = threadIdx.x;                 // [0,128)
    int col4 = half * 128 + c;           // [0,256) float4 col
    int start = offsets[node], cnt = counts[node];
    float d = fmaxf((float)cnt, 1.0f);
    const float4* hb = (const float4*)h;
    float ax = 0.f, ay = 0.f, az = 0.f, aw = 0.f;
    int j = 0;
    for (; j + 4 <= cnt; j += 4) {
        int s0 = adj[start + j + 0];
        int s1 = adj[start + j + 1];
        int s2 = adj[start + j + 2];
        int s3 = adj[start + j + 3];
        int o0 = old_idx[s0], o1 = old_idx[s1], o2 = old_idx[s2], o3 = old_idx[s3];
        float w0 = vals[s0], w1 = vals[s1], w2 = vals[s2], w3 = vals[s3];
        float4 v0 = hb[(size_t)o0 * 256 + col4];
        float4 v1 = hb[(size_t)o1 * 256 + col4];
        float4 v2 = hb[(size_t)o2 * 256 + col4];
        float4 v3 = hb[(size_t)o3 * 256 + col4];
        ax += (w0 * v0.x + w1 * v1.x) + (w2 * v2.x + w3 * v3.x);
        ay += (w0 * v0.y + w1 * v1.y) + (w2 * v2.y + w3 * v3.y);
        az += (w0 * v0.z + w1 * v1.z) + (w2 * v2.z + w3 * v3.z);
        aw += (w0 * v0.w + w1 * v1.w) + (w2 * v2.w + w3 * v3.w);
    }
    for (; j < cnt; ++j) {
        int s = adj[start + j];
        int o = old_idx[s];
        float w = vals[s];
        float4 v = hb[(size_t)o * 256 + col4];
        ax += w * v.x; ay += w * v.y; az += w * v.z; aw += w * v.w;
    }
    float inv = 1.0f / d;
    int on = old_idx[node];
    float vn = vals[node];
    float4 cv = hb[(size_t)on * 256 + col4];
    cv.x *= vn; cv.y *= vn; cv.z *= vn; cv.w *= vn;
    ushort_t* row = Abig + (size_t)node * 4096;
    int f = col4 * 4;
    ushort4 mh, ml, ch, cl;
    split1(ax * inv, mh.x, ml.x); split1(ay * inv, mh.y, ml.y);
    split1(az * inv, mh.z, ml.z); split1(aw * inv, mh.w, ml.w);
    split1(cv.x, ch.x, cl.x); split1(cv.y, ch.y, cl.y);
    split1(cv.z, ch.z, cl.z); split1(cv.w, ch.w, cl.w);
    *(ushort4*)&row[f]        = mh;
    *(ushort4*)&row[1024 + f] = ml;
    *(ushort4*)&row[2048 + f] = ch;
    *(ushort4*)&row[3072 + f] = cl;
}

__global__ __launch_bounds__(256) void pack_w_kernel(const float* __restrict__ Wl,
                                                     const float* __restrict__ Wr,
                                                     ushort_t* __restrict__ Wbig, int K) {
    int idx = blockIdx.x * 256 + threadIdx.x;
    int n = idx / K;
    int k = idx - n * K;
    ushort_t* row = Wbig + (size_t)n * (4 * K);
    float a = Wl[idx];
    ushort_t ah = f2bf(a);
    row[k] = ah;
    row[K + k] = f2bf(a - bf2f(ah));
    float b = Wr[idx];
    ushort_t bh = f2bf(b);
    row[2 * K + k] = bh;
    row[3 * K + k] = f2bf(b - bf2f(bh));
}

// ---------------- MFMA GEMM, XCD-local panels + partial-score epilogue ----------------
// 1D grid of npanels*8 blocks (npanels % 8 == 0). Decode keeps all 8 col-blocks of a
// row panel on ONE XCD (dispatch round-robin gid%8) -> each XCD reads only its A slice.
// Epilogue: h=relu(acc+bias) store + partial dot(h,p) stored (no atomics) to
// sp[(cb*2 + waveHalf) * SPROWS + row].

__global__ __launch_bounds__(256) void gemm_mfma(const ushort_t* __restrict__ Ab,
                                                 const ushort_t* __restrict__ Wb,
                                                 const float* __restrict__ bias,
                                                 float* __restrict__ C,
                                                 float* __restrict__ sp,
                                                 const float* __restrict__ pvec,
                                                 int K, int npanels) {
    __shared__ ushort_t lA0[4096];
    __shared__ ushort_t lA1[4096];
    __shared__ ushort_t lB0[4096];
    __shared__ ushort_t lB1[4096];
    const int LD = 4 * K;
    int tid = threadIdx.x;
    int lane = tid & 63;
    int w = tid >> 6;
    int wr = (w >> 1) * 64, wc = (w & 1) * 64;

    int gid = blockIdx.x;
    int xcd = gid & 7;
    int idx = gid >> 3;                       // [0, npanels)
    int panel = xcd * (npanels >> 3) + (idx >> 3);
    int cb = idx & 7;
    int m0 = panel * 128, n0 = cb * 128;

    int srow = tid >> 2;
    int gq = (tid & 3) ^ ((tid >> 2) & 3) ^ ((tid >> 4) & 3);
    const ushort_t* Ag = Ab + (size_t)(m0 + srow) * LD + gq * 8;
    const ushort_t* Bg = Wb + (size_t)(n0 + srow) * LD + gq * 8;
    ushort_t* lA0p = &lA0[tid * 8];
    ushort_t* lA1p = &lA1[tid * 8];
    ushort_t* lB0p = &lB0[tid * 8];
    ushort_t* lB1p = &lB1[tid * 8];
    const size_t rstep = (size_t)64 * LD;

    int qsw = (lane >> 4) ^ (lane & 3) ^ ((lane >> 2) & 3);
    int aidx = (wr + (lane & 15)) * 32 + qsw * 8;
    int bidx = (wc + (lane & 15)) * 32 + qsw * 8;

    f32x4 acc[4][4];
#pragma unroll
    for (int i = 0; i < 4; ++i)
#pragma unroll
        for (int j = 0; j < 4; ++j) acc[i][j] = (f32x4){0.f, 0.f, 0.f, 0.f};

    for (int ss = 0; ss < 2; ++ss) {
        const ushort_t* Ah = Ag + ss * 2 * K;
        const ushort_t* Bh = Bg + ss * 2 * K;
        for (int kk = 0; kk < K; kk += 32) {
            __syncthreads();
            gll16(Ah + kk, lA0p);
            gll16(Ah + kk + rstep, lA0p + 2048);
            gll16(Ah + K + kk, lA1p);
            gll16(Ah + K + kk + rstep, lA1p + 2048);
            gll16(Bh + kk, lB0p);
            gll16(Bh + kk + rstep, lB0p + 2048);
            gll16(Bh + K + kk, lB1p);
            gll16(Bh + K + kk + rstep, lB1p + 2048);
            __syncthreads();
            bf16x8 a0[4], a1[4], b0[4], b1[4];
#pragma unroll
            for (int i = 0; i < 4; ++i) a0[i] = *(const bf16x8*)&lA0[aidx + i * 512];
#pragma unroll
            for (int j = 0; j < 4; ++j) b0[j] = *(const bf16x8*)&lB0[bidx + j * 512];
#pragma unroll
            for (int i = 0; i < 4; ++i)
#pragma unroll
                for (int j = 0; j < 4; ++j)
                    acc[i][j] = __builtin_amdgcn_mfma_f32_16x16x32_bf16(a0[i], b0[j], acc[i][j], 0, 0, 0);
#pragma unroll
            for (int i = 0; i < 4; ++i) a1[i] = *(const bf16x8*)&lA1[aidx + i * 512];
#pragma unroll
            for (int i = 0; i < 4; ++i)
#pragma unroll
                for (int j = 0; j < 4; ++j)
                    acc[i][j] = __builtin_amdgcn_mfma_f32_16x16x32_bf16(a1[i], b0[j], acc[i][j], 0, 0, 0);
#pragma unroll
            for (int j = 0; j < 4; ++j) b1[j] = *(const bf16x8*)&lB1[bidx + j * 512];
#pragma unroll
            for (int i = 0; i < 4; ++i)
#pragma unroll
                for (int j = 0; j < 4; ++j)
                    acc[i][j] = __builtin_amdgcn_mfma_f32_16x16x32_bf16(a0[i], b1[j], acc[i][j], 0, 0, 0);
        }
    }

    float bj[4], pj[4];
#pragma unroll
    for (int j = 0; j < 4; ++j) {
        int col = n0 + wc + j * 16 + (lane & 15);
        bj[j] = bias[col];
        pj[j] = pvec[col];
    }
    int slot = cb * 2 + (wc >> 6);           // [0,16): unique (colblock, wave-half)
#pragma unroll
    for (int i = 0; i < 4; ++i) {
        int row0 = m0 + wr + i * 16 + (lane >> 4) * 4;
        float sacc[4] = {0.f, 0.f, 0.f, 0.f};
#pragma unroll
        for (int j = 0; j < 4; ++j) {
            int col = n0 + wc + j * 16 + (lane & 15);
#pragma unroll
            for (int r = 0; r < 4; ++r) {
                float v = acc[i][j][r] + bj[j];
                v = v > 0.f ? v : 0.f;
                C[(size_t)(row0 + r) * 1024 + col] = v;
                sacc[r] += v * pj[j];
            }
        }
#pragma unroll
        for (int r = 0; r < 4; ++r) {
            float sv_ = sacc[r];
            sv_ += __shfl_xor(sv_, 1);
            sv_ += __shfl_xor(sv_, 2);
            sv_ += __shfl_xor(sv_, 4);
            sv_ += __shfl_xor(sv_, 8);
            if ((lane & 15) == 0) sp[slot * SPROWS_ + row0 + r] = sv_;
        }
    }
}

// ---------------- scoring norms + top-k by rank ----------------

__global__ __launch_bounds__(256) void pnorm3_kernel(const float* __restrict__ p1,
                                                     const float* __restrict__ p2,
                                                     const float* __restrict__ p3,
                                                     float* __restrict__ out) {
    const float* p = blockIdx.x == 0 ? p1 : (blockIdx.x == 1 ? p2 : p3);
    __shared__ float red[256];
    float a = 0.f;
    for (int i = threadIdx.x; i < 1024; i += 256) { float v = p[i]; a += v * v; }
    red[threadIdx.x] = a;
    __syncthreads();
    for (int s = 128; s > 0; s >>= 1) {
        if (threadIdx.x < s) red[threadIdx.x] += red[threadIdx.x + s];
        __syncthreads();
    }
    if (threadIdx.x == 0) out[blockIdx.x] = sqrtf(red[0]);
}

// one block per graph; sums 16 score partials; rank selection; zeros next counts.
__global__ __launch_bounds__(1024) void topk_rank(const float* __restrict__ sp, int n, int k,
                                                  const float* __restrict__ pn,
                                                  int* __restrict__ old_idx, float* __restrict__ vals,
                                                  int* __restrict__ remap, int* __restrict__ counts) {
    __shared__ float sv[1024];
    int b = blockIdx.x, t = threadIdx.x;
    float mine = -INFINITY;
    if (t < n) {
        int base = b * n + t;
        float s0 = 0.f;
#pragma unroll
        for (int c = 0; c < 16; ++c) s0 += sp[c * SPROWS_ + base];
        mine = s0;
        remap[base] = -1;
    }
    sv[t] = mine;
    __syncthreads();
    int rank = 0;
#pragma unroll 4
    for (int j = 0; j < 1024; ++j) {
        float o = sv[j];
        rank += (o > mine) || (o == mine && j < t);
    }
    if (t < n && rank < k) {
        int old = b * n + t;
        int pos = b * k + rank;
        old_idx[pos] = old;
        vals[pos] = tanhf(mine / pn[0]);
        remap[old] = pos;
    }
    if (t < k) counts[b * k + t] = 0;
}

// gated readout straight from h via (old_idx, vals) — no materialized pooled buffer
__global__ __launch_bounds__(256) void readout_gated(const float* __restrict__ h,
                                                     const int* __restrict__ old_idx,
                                                     const float* __restrict__ vals,
                                                     int k, float* __restrict__ out) {
    int b = blockIdx.x;
    int c = threadIdx.x;
    const float4* hb = (const float4*)h;
    const int* oi = old_idx + b * k;
    const float* vv = vals + b * k;
    float4 mx = {-INFINITY, -INFINITY, -INFINITY, -INFINITY};
    float4 sm = {0.f, 0.f, 0.f, 0.f};
    int i = 0;
    for (; i + 4 <= k; i += 4) {
        int o0 = oi[i], o1 = oi[i + 1], o2 = oi[i + 2], o3 = oi[i + 3];
        float w0 = vv[i], w1 = vv[i + 1], w2 = vv[i + 2], w3 = vv[i + 3];
        float4 v0 = hb[(size_t)o0 * 256 + c];
        float4 v1 = hb[(size_t)o1 * 256 + c];
        float4 v2 = hb[(size_t)o2 * 256 + c];
        float4 v3 = hb[(size_t)o3 * 256 + c];
        v0.x *= w0; v0.y *= w0; v0.z *= w0; v0.w *= w0;
        v1.x *= w1; v1.y *= w1; v1.z *= w1; v1.w *= w1;
        v2.x *= w2; v2.y *= w2; v2.z *= w2; v2.w *= w2;
        v3.x *= w3; v3.y *= w3; v3.z *= w3; v3.w *= w3;
        mx.x = fmaxf(fmaxf(fmaxf(mx.x, v0.x), fmaxf(v1.x, v2.x)), v3.x);
        mx.y = fmaxf(fmaxf(fmaxf(mx.y, v0.y), fmaxf(v1.y, v2.y)), v3.y);
        mx.z = fmaxf(fmaxf(fmaxf(mx.z, v0.z), fmaxf(v1.z, v2.z)), v3.z);
        mx.w = fmaxf(fmaxf(fmaxf(mx.w, v0.w), fmaxf(v1.w, v2.w)), v3.w);
        sm.x += (v0.x + v1.x) + (v2.x + v3.x);
        sm.y += (v0.y + v1.y) + (v2.y + v3.y);
        sm.z += (v0.z + v1.z) + (v2.z + v3.z);
        sm.w += (v0.w + v1.w) + (v2.w + v3.w);
    }
    for (; i < k; ++i) {
        int o = oi[i];
        float w = vv[i];
        float4 v = hb[(size_t)o * 256 + c];
        v.x *= w; v.y *= w; v.z *= w; v.w *= w;
        mx.x = fmaxf(mx.x, v.x); mx.y = fmaxf(mx.y, v.y);
        mx.z = fmaxf(mx.z, v.z); mx.w = fmaxf(mx.w, v.w);
        sm.x += v.x; sm.y += v.y; sm.z += v.z; sm.w += v.w;
    }
    float invk = 1.0f / (float)k;
    float* o0 = out + (size_t)b * 2048 + c * 4;
    o0[0] += mx.x; o0[1] += mx.y; o0[2] += mx.z; o0[3] += mx.w;
    float* o1 = o0 + 1024;
    o1[0] += sm.x * invk; o1[1] += sm.y * invk; o1[2] += sm.z * invk; o1[3] += sm.w * invk;
}

// ---------------- host-side layer driver ----------------

static void run_layer(const float* gatherSrc, int K, int M, int Mp, int n_per, int k_keep,
                      const float* Wl, const float* bias, const float* Wr,
                      const float* p, const float* pn, bool first, bool last,
                      ushort_t* Abig, ushort_t* Wbig, float* bufOut,
                      int* esrc, int* edst, int* emask,
                      int* counts, int* offsets, int* cursor, int* adj,
                      float* sp, int* old_idx, float* vals, int* remap,
                      float* out, hipStream_t stream) {
    scan16_kernel<<<1, 1024, 0, stream>>>(counts, offsets, cursor, M);
    fill_kernel<<<E_ / 256, 256, 0, stream>>>(esrc, edst, emask, cursor, adj);
    if (Mp > M)
        hipMemsetAsync(Abig + (size_t)M * 4 * K, 0, (size_t)(Mp - M) * 8 * K, stream);
    if (first)
        agg1_k512<<<16384, 128, 0, stream>>>(gatherSrc, adj, offsets, counts, Abig);
    else
        agg23_k1024<<<32 * n_per, 128, 0, stream>>>(gatherSrc, adj, offsets, counts,
                                                    old_idx, vals, Abig, n_per);
    pack_w_kernel<<<(1024 * K) / 256, 256, 0, stream>>>(Wl, Wr, Wbig, K);
    int npanels = Mp / 128;
    gemm_mfma<<<npanels * 8, 256, 0, stream>>>(Abig, Wbig, bias, bufOut, sp, p, K, npanels);
    topk_rank<<<B_, 1024, 0, stream>>>(sp, n_per, k_keep, pn, old_idx, vals, remap, counts);
    readout_gated<<<B_, 256, 0, stream>>>(bufOut, old_idx, vals, k_keep, out);
    if (!last)
        edge_update_count<<<E_ / 256, 256, 0, stream>>>(esrc, edst, emask, remap, counts);
}

extern "C" void kernel_launch(void* const* d_in, const int* in_sizes, int n_in,
                              void* d_out, int out_size, void* d_ws, size_t ws_size,
                              hipStream_t stream) {
    const float* x   = (const float*)d_in[0];
    const int*   ei  = (const int*)d_in[1];
    const float* W1l = (const float*)d_in[3];
    const float* b1  = (const float*)d_in[4];
    const float* W1r = (const float*)d_in[5];
    const float* p1  = (const float*)d_in[6];
    const float* W2l = (const float*)d_in[7];
    const float* b2  = (const float*)d_in[8];
    const float* W2r = (const float*)d_in[9];
    const float* p2  = (const float*)d_in[10];
    const float* W3l = (const float*)d_in[11];
    const float* b3  = (const float*)d_in[12];
    const float* W3r = (const float*)d_in[13];
    const float* p3  = (const float*)d_in[14];
    float* out = (float*)d_out;

    char* ws = (char*)d_ws;
    size_t off = 0;
    float* bufOut = (float*)(ws + off); off += (size_t)MP1_ * 1024 * 4;            // 64 MB
    ushort_t* Abig = (ushort_t*)(ws + off); off += (size_t)MP2_ * 4096 * 2;        // 109 MB
    ushort_t* Wbig = (ushort_t*)(ws + off); off += (size_t)1024 * 4096 * 2;        // 8 MB
    float* sp = (float*)(ws + off); off += (size_t)16 * SPROWS_ * 4;               // 1 MB
    char* misc = ws + off;
    int*   counts = (int*)(misc + 0 * 65536);
    int*   offsets= (int*)(misc + 1 * 65536);
    int*   cursor = (int*)(misc + 2 * 65536);
    int*   old_idx= (int*)(misc + 3 * 65536);
    float* vals   = (float*)(misc + 4 * 65536);
    int*   remap  = (int*)(misc + 5 * 65536);
    float* pnormv = (float*)(misc + 6 * 65536);
    int*   adj    = (int*)(misc + 7 * 65536);
    int*   esrc   = (int*)(misc + 7 * 65536 + 1 * 1048576);
    int*   edst   = (int*)(misc + 7 * 65536 + 2 * 1048576);
    int*   emask  = (int*)(misc + 7 * 65536 + 3 * 1048576);

    hipMemsetAsync(d_out, 0, (size_t)out_size * sizeof(float), stream);
    hipMemsetAsync(counts, 0, 65536, stream);
    pnorm3_kernel<<<3, 256, 0, stream>>>(p1, p2, p3, pnormv);
    init_edges_count<<<E_ / 256, 256, 0, stream>>>(ei, esrc, edst, emask, counts);

    // layer 1: gather from x (K=512), M=16384, pool 1024->820
    run_layer(x, FEAT_, M1_, MP1_, NP_, K1_, W1l, b1, W1r, p1, pnormv + 0, true, false,
              Abig, Wbig, bufOut, esrc, edst, emask,
              counts, offsets, cursor, adj, sp, old_idx, vals, remap, out, stream);
    // layer 2: gather gated h1 from bufOut via (old_idx, vals) of layer 1 pool
    run_layer(bufOut, H_, M2_, MP2_, K1_, K2_, W2l, b2, W2r, p2, pnormv + 1, false, false,
              Abig, Wbig, bufOut, esrc, edst, emask,
              counts, offsets, cursor, adj, sp, old_idx, vals, remap, out, stream);
    // layer 3: gather gated h2 from bufOut via (old_idx, vals) of layer 2 pool
    run_layer(bufOut, H_, M3_, MP3_, K2_, K3_, W3l, b3, W3r, p3, pnormv + 2, false, true,
              Abig, Wbig, bufOut, esrc, edst, emask,
              counts, offsets, cursor, adj, sp, old_idx, vals, remap, out, stream);
}

// Round 7
// 1042.037 us; speedup vs baseline: 1.1371x; 1.1020x over previous
//
#include <hip/hip_runtime.h>
#include <math.h>

// Problem constants (fixed by reference)
#define B_    16
#define NP_   1024
#define FEAT_ 512
#define H_    1024
#define E_    262144          // B*NP*DEG
#define EPG_  16384           // edges per graph (edge list is graph-sorted)
#define K1_   820             // ceil(0.8*1024)
#define K2_   656             // ceil(0.8*820)
#define K3_   525             // ceil(0.8*656)
#define M1_   16384           // B*NP
#define M2_   13120           // B*K1
#define M3_   10496           // B*K2
// padded row counts: panels (Mp/128) divisible by 8 for XCD-local mapping
#define MP1_  16384           // 128 panels
#define MP2_  13312           // 104 panels
#define MP3_  11264           // 88 panels
#define SPROWS_ 16384         // scoresPart row stride

typedef unsigned short ushort_t;
typedef __bf16 bf16x8 __attribute__((ext_vector_type(8)));
typedef float f32x4 __attribute__((ext_vector_type(4)));

// ---- bf16 split helpers (RNE) ----
__device__ inline ushort_t f2bf(float f) {
    unsigned u = __float_as_uint(f);
    u += 0x7FFF + ((u >> 16) & 1);
    return (ushort_t)(u >> 16);
}
__device__ inline float bf2f(ushort_t h) {
    return __uint_as_float(((unsigned)h) << 16);
}
__device__ inline void split1(float v, ushort_t& hi, ushort_t& lo) {
    hi = f2bf(v);
    lo = f2bf(v - bf2f(hi));
}

__device__ inline void gll16(const void* g, void* l) {
    __builtin_amdgcn_global_load_lds((__attribute__((address_space(1))) void*)g,
                                     (__attribute__((address_space(3))) void*)l, 16, 0, 0);
}

// ---------------- upfront: edges + layer-1 CSR ----------------

__global__ void init_edges_count(const int* __restrict__ ei, int* __restrict__ esrc,
                                 int* __restrict__ edst, int* __restrict__ emask,
                                 int* __restrict__ counts) {
    int e = blockIdx.x * 256 + threadIdx.x;
    int s = ei[e], d = ei[E_ + e];
    esrc[e] = s;
    edst[e] = d;
    emask[e] = 1;
    atomicAdd(&counts[d], 1);
}

// per-graph scan (16 blocks): offsets/cursor into graph-b adj region [b*EPG, ...)
__global__ __launch_bounds__(1024) void scan_g16(const int* __restrict__ counts,
                                                 int* __restrict__ offsets,
                                                 int* __restrict__ cursor, int n) {
    __shared__ int tmp[1024];
    int b = blockIdx.x, t = threadIdx.x;
    int v = (t < n) ? counts[b * n + t] : 0;
    tmp[t] = v;
    __syncthreads();
    for (int off = 1; off < 1024; off <<= 1) {
        int tv = (t >= off) ? tmp[t - off] : 0;
        __syncthreads();
        tmp[t] += tv;
        __syncthreads();
    }
    int excl = tmp[t] - v;
    if (t < n) {
        int o = b * EPG_ + excl;
        offsets[b * n + t] = o;
        cursor[b * n + t] = o;
    }
}

__global__ void fill_kernel(const int* __restrict__ esrc, const int* __restrict__ edst,
                            const int* __restrict__ emask, int* __restrict__ cursor,
                            int* __restrict__ adj) {
    int e = blockIdx.x * 256 + threadIdx.x;
    if (emask[e]) {
        int pos = atomicAdd(&cursor[edst[e]], 1);
        adj[pos] = esrc[e];
    }
}

// ---------------- aggregation + pack (col-split halves, XCD-pinned) ----------------
// Abig row (4K cols bf16): [agg_hi(K) | agg_lo(K) | cur_hi(K) | cur_lo(K)]

// Layer 1: source = x (K=512). 128 thr: 2 nodes x 64 float4 cols (one half).
__global__ __launch_bounds__(128) void agg1_k512(const float* __restrict__ x,
                                                 const int* __restrict__ adj,
                                                 const int* __restrict__ offsets,
                                                 const int* __restrict__ counts,
                                                 ushort_t* __restrict__ Abig) {
    int gid = blockIdx.x;
    int xcd = gid & 7;
    int u = gid >> 3;
    int half = u & 1;
    int pi = u >> 1;
    int gsel = (pi >= 512) ? 1 : 0;
    int g = xcd + (gsel << 3);
    int node = g * 1024 + (pi - (gsel << 9)) * 2 + (threadIdx.x >> 6);
    int c = threadIdx.x & 63;
    int col4 = half * 64 + c;
    int start = offsets[node], cnt = counts[node];
    float d = fmaxf((float)cnt, 1.0f);
    const float4* xb = (const float4*)x;
    float ax = 0.f, ay = 0.f, az = 0.f, aw = 0.f;
    int j = 0;
    for (; j + 4 <= cnt; j += 4) {
        int s0 = adj[start + j + 0];
        int s1 = adj[start + j + 1];
        int s2 = adj[start + j + 2];
        int s3 = adj[start + j + 3];
        float4 v0 = xb[(size_t)s0 * 128 + col4];
        float4 v1 = xb[(size_t)s1 * 128 + col4];
        float4 v2 = xb[(size_t)s2 * 128 + col4];
        float4 v3 = xb[(size_t)s3 * 128 + col4];
        ax += (v0.x + v1.x) + (v2.x + v3.x);
        ay += (v0.y + v1.y) + (v2.y + v3.y);
        az += (v0.z + v1.z) + (v2.z + v3.z);
        aw += (v0.w + v1.w) + (v2.w + v3.w);
    }
    for (; j < cnt; ++j) {
        float4 v = xb[(size_t)adj[start + j] * 128 + col4];
        ax += v.x; ay += v.y; az += v.z; aw += v.w;
    }
    float inv = 1.0f / d;
    float4 cv = xb[(size_t)node * 128 + col4];
    ushort_t* row = Abig + (size_t)node * 2048;
    int f = col4 * 4;
    ushort4 mh, ml, ch, cl;
    split1(ax * inv, mh.x, ml.x); split1(ay * inv, mh.y, ml.y);
    split1(az * inv, mh.z, ml.z); split1(aw * inv, mh.w, ml.w);
    split1(cv.x, ch.x, cl.x); split1(cv.y, ch.y, cl.y);
    split1(cv.z, ch.z, cl.z); split1(cv.w, ch.w, cl.w);
    *(ushort4*)&row[f]        = mh;
    *(ushort4*)&row[512 + f]  = ml;
    *(ushort4*)&row[1024 + f] = ch;
    *(ushort4*)&row[1536 + f] = cl;
}

// Layers 2/3: source = gated prev-layer h via (old_idx, vals). K=1024.
__global__ __launch_bounds__(128) void agg23_k1024(const float* __restrict__ h,
                                                   const int* __restrict__ adj,
                                                   const int* __restrict__ offsets,
                                                   const int* __restrict__ counts,
                                                   const int* __restrict__ old_idx,
                                                   const float* __restrict__ vals,
                                                   ushort_t* __restrict__ Abig,
                                                   int n_per) {
    int gid = blockIdx.x;
    int xcd = gid & 7;
    int u = gid >> 3;
    int half = u & 1;
    int nl = u >> 1;
    int gsel = (nl >= n_per) ? 1 : 0;
    int g = xcd + (gsel << 3);
    int node = g * n_per + nl - gsel * n_per;
    int c = threadIdx.x;
    int col4 = half * 128 + c;
    int start = offsets[node], cnt = counts[node];
    float d = fmaxf((float)cnt, 1.0f);
    const float4* hb = (const float4*)h;
    float ax = 0.f, ay = 0.f, az = 0.f, aw = 0.f;
    int j = 0;
    for (; j + 4 <= cnt; j += 4) {
        int s0 = adj[start + j + 0];
        int s1 = adj[start + j + 1];
        int s2 = adj[start + j + 2];
        int s3 = adj[start + j + 3];
        int o0 = old_idx[s0], o1 = old_idx[s1], o2 = old_idx[s2], o3 = old_idx[s3];
        float w0 = vals[s0], w1 = vals[s1], w2 = vals[s2], w3 = vals[s3];
        float4 v0 = hb[(size_t)o0 * 256 + col4];
        float4 v1 = hb[(size_t)o1 * 256 + col4];
        float4 v2 = hb[(size_t)o2 * 256 + col4];
        float4 v3 = hb[(size_t)o3 * 256 + col4];
        ax += (w0 * v0.x + w1 * v1.x) + (w2 * v2.x + w3 * v3.x);
        ay += (w0 * v0.y + w1 * v1.y) + (w2 * v2.y + w3 * v3.y);
        az += (w0 * v0.z + w1 * v1.z) + (w2 * v2.z + w3 * v3.z);
        aw += (w0 * v0.w + w1 * v1.w) + (w2 * v2.w + w3 * v3.w);
    }
    for (; j < cnt; ++j) {
        int s = adj[start + j];
        int o = old_idx[s];
        float w = vals[s];
        float4 v = hb[(size_t)o * 256 + col4];
        ax += w * v.x; ay += w * v.y; az += w * v.z; aw += w * v.w;
    }
    float inv = 1.0f / d;
    int on = old_idx[node];
    float vn = vals[node];
    float4 cv = hb[(size_t)on * 256 + col4];
    cv.x *= vn; cv.y *= vn; cv.z *= vn; cv.w *= vn;
    ushort_t* row = Abig + (size_t)node * 4096;
    int f = col4 * 4;
    ushort4 mh, ml, ch, cl;
    split1(ax * inv, mh.x, ml.x); split1(ay * inv, mh.y, ml.y);
    split1(az * inv, mh.z, ml.z); split1(aw * inv, mh.w, ml.w);
    split1(cv.x, ch.x, cl.x); split1(cv.y, ch.y, cl.y);
    split1(cv.z, ch.z, cl.z); split1(cv.w, ch.w, cl.w);
    *(ushort4*)&row[f]        = mh;
    *(ushort4*)&row[1024 + f] = ml;
    *(ushort4*)&row[2048 + f] = ch;
    *(ushort4*)&row[3072 + f] = cl;
}

// ---------------- pack all 3 weight pairs upfront ----------------
__global__ __launch_bounds__(256) void pack_w_all(const float* __restrict__ W1l, const float* __restrict__ W1r,
                                                  const float* __restrict__ W2l, const float* __restrict__ W2r,
                                                  const float* __restrict__ W3l, const float* __restrict__ W3r,
                                                  ushort_t* __restrict__ Wb1, ushort_t* __restrict__ Wb2,
                                                  ushort_t* __restrict__ Wb3) {
    int idx = blockIdx.x * 256 + threadIdx.x;      // [0, 512K + 1M + 1M)
    const float *Wl, *Wr; ushort_t* Wbig; int K;
    if (idx < 524288) { Wl = W1l; Wr = W1r; Wbig = Wb1; K = 512; }
    else if (idx < 524288 + 1048576) { idx -= 524288; Wl = W2l; Wr = W2r; Wbig = Wb2; K = 1024; }
    else { idx -= 524288 + 1048576; Wl = W3l; Wr = W3r; Wbig = Wb3; K = 1024; }
    int n = idx / K;
    int k = idx - n * K;
    ushort_t* row = Wbig + (size_t)n * (4 * K);
    float a = Wl[idx];
    ushort_t ah = f2bf(a);
    row[k] = ah;
    row[K + k] = f2bf(a - bf2f(ah));
    float b = Wr[idx];
    ushort_t bh = f2bf(b);
    row[2 * K + k] = bh;
    row[3 * K + k] = f2bf(b - bf2f(bh));
}

// ---------------- MFMA GEMM, XCD-local panels + partial-score epilogue ----------------

__global__ __launch_bounds__(256) void gemm_mfma(const ushort_t* __restrict__ Ab,
                                                 const ushort_t* __restrict__ Wb,
                                                 const float* __restrict__ bias,
                                                 float* __restrict__ C,
                                                 float* __restrict__ sp,
                                                 const float* __restrict__ pvec,
                                                 int K, int npanels) {
    __shared__ ushort_t lA0[4096];
    __shared__ ushort_t lA1[4096];
    __shared__ ushort_t lB0[4096];
    __shared__ ushort_t lB1[4096];
    const int LD = 4 * K;
    int tid = threadIdx.x;
    int lane = tid & 63;
    int w = tid >> 6;
    int wr = (w >> 1) * 64, wc = (w & 1) * 64;

    int gid = blockIdx.x;
    int xcd = gid & 7;
    int idx = gid >> 3;
    int panel = xcd * (npanels >> 3) + (idx >> 3);
    int cb = idx & 7;
    int m0 = panel * 128, n0 = cb * 128;

    int srow = tid >> 2;
    int gq = (tid & 3) ^ ((tid >> 2) & 3) ^ ((tid >> 4) & 3);
    const ushort_t* Ag = Ab + (size_t)(m0 + srow) * LD + gq * 8;
    const ushort_t* Bg = Wb + (size_t)(n0 + srow) * LD + gq * 8;
    ushort_t* lA0p = &lA0[tid * 8];
    ushort_t* lA1p = &lA1[tid * 8];
    ushort_t* lB0p = &lB0[tid * 8];
    ushort_t* lB1p = &lB1[tid * 8];
    const size_t rstep = (size_t)64 * LD;

    int qsw = (lane >> 4) ^ (lane & 3) ^ ((lane >> 2) & 3);
    int aidx = (wr + (lane & 15)) * 32 + qsw * 8;
    int bidx = (wc + (lane & 15)) * 32 + qsw * 8;

    f32x4 acc[4][4];
#pragma unroll
    for (int i = 0; i < 4; ++i)
#pragma unroll
        for (int j = 0; j < 4; ++j) acc[i][j] = (f32x4){0.f, 0.f, 0.f, 0.f};

    for (int ss = 0; ss < 2; ++ss) {
        const ushort_t* Ah = Ag + ss * 2 * K;
        const ushort_t* Bh = Bg + ss * 2 * K;
        for (int kk = 0; kk < K; kk += 32) {
            __syncthreads();
            gll16(Ah + kk, lA0p);
            gll16(Ah + kk + rstep, lA0p + 2048);
            gll16(Ah + K + kk, lA1p);
            gll16(Ah + K + kk + rstep, lA1p + 2048);
            gll16(Bh + kk, lB0p);
            gll16(Bh + kk + rstep, lB0p + 2048);
            gll16(Bh + K + kk, lB1p);
            gll16(Bh + K + kk + rstep, lB1p + 2048);
            __syncthreads();
            bf16x8 a0[4], a1[4], b0[4], b1[4];
#pragma unroll
            for (int i = 0; i < 4; ++i) a0[i] = *(const bf16x8*)&lA0[aidx + i * 512];
#pragma unroll
            for (int j = 0; j < 4; ++j) b0[j] = *(const bf16x8*)&lB0[bidx + j * 512];
#pragma unroll
            for (int i = 0; i < 4; ++i)
#pragma unroll
                for (int j = 0; j < 4; ++j)
                    acc[i][j] = __builtin_amdgcn_mfma_f32_16x16x32_bf16(a0[i], b0[j], acc[i][j], 0, 0, 0);
#pragma unroll
            for (int i = 0; i < 4; ++i) a1[i] = *(const bf16x8*)&lA1[aidx + i * 512];
#pragma unroll
            for (int i = 0; i < 4; ++i)
#pragma unroll
                for (int j = 0; j < 4; ++j)
                    acc[i][j] = __builtin_amdgcn_mfma_f32_16x16x32_bf16(a1[i], b0[j], acc[i][j], 0, 0, 0);
#pragma unroll
            for (int j = 0; j < 4; ++j) b1[j] = *(const bf16x8*)&lB1[bidx + j * 512];
#pragma unroll
            for (int i = 0; i < 4; ++i)
#pragma unroll
                for (int j = 0; j < 4; ++j)
                    acc[i][j] = __builtin_amdgcn_mfma_f32_16x16x32_bf16(a0[i], b1[j], acc[i][j], 0, 0, 0);
        }
    }

    float bj[4], pj[4];
#pragma unroll
    for (int j = 0; j < 4; ++j) {
        int col = n0 + wc + j * 16 + (lane & 15);
        bj[j] = bias[col];
        pj[j] = pvec[col];
    }
    int slot = cb * 2 + (wc >> 6);
#pragma unroll
    for (int i = 0; i < 4; ++i) {
        int row0 = m0 + wr + i * 16 + (lane >> 4) * 4;
        float sacc[4] = {0.f, 0.f, 0.f, 0.f};
#pragma unroll
        for (int j = 0; j < 4; ++j) {
            int col = n0 + wc + j * 16 + (lane & 15);
#pragma unroll
            for (int r = 0; r < 4; ++r) {
                float v = acc[i][j][r] + bj[j];
                v = v > 0.f ? v : 0.f;
                C[(size_t)(row0 + r) * 1024 + col] = v;
                sacc[r] += v * pj[j];
            }
        }
#pragma unroll
        for (int r = 0; r < 4; ++r) {
            float sv_ = sacc[r];
            sv_ += __shfl_xor(sv_, 1);
            sv_ += __shfl_xor(sv_, 2);
            sv_ += __shfl_xor(sv_, 4);
            sv_ += __shfl_xor(sv_, 8);
            if ((lane & 15) == 0) sp[slot * SPROWS_ + row0 + r] = sv_;
        }
    }
}

// ---------------- pnorms ----------------

__global__ __launch_bounds__(256) void pnorm3_kernel(const float* __restrict__ p1,
                                                     const float* __restrict__ p2,
                                                     const float* __restrict__ p3,
                                                     float* __restrict__ out) {
    const float* p = blockIdx.x == 0 ? p1 : (blockIdx.x == 1 ? p2 : p3);
    __shared__ float red[256];
    float a = 0.f;
    for (int i = threadIdx.x; i < 1024; i += 256) { float v = p[i]; a += v * v; }
    red[threadIdx.x] = a;
    __syncthreads();
    for (int s = 128; s > 0; s >>= 1) {
        if (threadIdx.x < s) red[threadIdx.x] += red[threadIdx.x + s];
        __syncthreads();
    }
    if (threadIdx.x == 0) out[blockIdx.x] = sqrtf(red[0]);
}

// ---------------- fused tail: topk + readout + edge remap + CSR rebuild ----------------
// One block per graph (edges are graph-sorted: graph b owns [b*EPG, (b+1)*EPG)).

__global__ __launch_bounds__(1024) void tail_kernel(const float* __restrict__ sp,
                                                    const float* __restrict__ pn,
                                                    const float* __restrict__ h,
                                                    float* __restrict__ out,
                                                    int n, int k,
                                                    int* __restrict__ old_idx, float* __restrict__ vals,
                                                    int* __restrict__ esrc, int* __restrict__ edst,
                                                    int* __restrict__ emask,
                                                    int* __restrict__ counts, int* __restrict__ offsets,
                                                    int* __restrict__ adj, int do_edges) {
    __shared__ float sv[1024];
    __shared__ int   rmap[1024];
    __shared__ int   oi_s[1024];     // kept-node global row ids; later reused as scan buffer
    __shared__ float vv_s[1024];
    __shared__ int   cnt_s[1024];    // degree counts; later reused as fill cursor
    __shared__ float4 rmx[4][256];
    __shared__ float4 rsm[4][256];
    int b = blockIdx.x, t = threadIdx.x;

    // phase 1: sum score partials, rank-select (stable descending top-k)
    float mine = -INFINITY;
    if (t < n) {
        int base = b * n + t;
        float s0 = 0.f;
#pragma unroll
        for (int c = 0; c < 16; ++c) s0 += sp[c * SPROWS_ + base];
        mine = s0;
    }
    sv[t] = mine;
    cnt_s[t] = 0;
    __syncthreads();
    int rank = 0;
#pragma unroll 4
    for (int j = 0; j < 1024; ++j) {
        float o = sv[j];
        rank += (o > mine) || (o == mine && j < t);
    }
    bool kept = (t < n) && (rank < k);
    rmap[t] = kept ? rank : -1;
    if (kept) {
        float tv = tanhf(mine / pn[0]);
        oi_s[rank] = b * n + t;
        vv_s[rank] = tv;
        old_idx[b * k + rank] = b * n + t;
        vals[b * k + rank] = tv;
    }
    __syncthreads();

    // phase 2: gated readout (4 row-groups x 256 float4 cols), accumulate to out
    {
        int g = t >> 8, c = t & 255;
        const float4* hb = (const float4*)h;
        float4 mx = {-INFINITY, -INFINITY, -INFINITY, -INFINITY};
        float4 sm = {0.f, 0.f, 0.f, 0.f};
        for (int i = g; i < k; i += 4) {
            int o = oi_s[i];
            float wgt = vv_s[i];
            float4 v = hb[(size_t)o * 256 + c];
            v.x *= wgt; v.y *= wgt; v.z *= wgt; v.w *= wgt;
            mx.x = fmaxf(mx.x, v.x); mx.y = fmaxf(mx.y, v.y);
            mx.z = fmaxf(mx.z, v.z); mx.w = fmaxf(mx.w, v.w);
            sm.x += v.x; sm.y += v.y; sm.z += v.z; sm.w += v.w;
        }
        rmx[g][c] = mx; rsm[g][c] = sm;
    }
    __syncthreads();
    if (t < 256) {
        int c = t;
        float4 m0 = rmx[0][c], m1 = rmx[1][c], m2 = rmx[2][c], m3 = rmx[3][c];
        float4 s0 = rsm[0][c], s1 = rsm[1][c], s2 = rsm[2][c], s3 = rsm[3][c];
        float invk = 1.0f / (float)k;
        float* o0 = out + (size_t)b * 2048 + c * 4;
        o0[0] += fmaxf(fmaxf(m0.x, m1.x), fmaxf(m2.x, m3.x));
        o0[1] += fmaxf(fmaxf(m0.y, m1.y), fmaxf(m2.y, m3.y));
        o0[2] += fmaxf(fmaxf(m0.z, m1.z), fmaxf(m2.z, m3.z));
        o0[3] += fmaxf(fmaxf(m0.w, m1.w), fmaxf(m2.w, m3.w));
        float* o1 = o0 + 1024;
        o1[0] += ((s0.x + s1.x) + (s2.x + s3.x)) * invk;
        o1[1] += ((s0.y + s1.y) + (s2.y + s3.y)) * invk;
        o1[2] += ((s0.z + s1.z) + (s2.z + s3.z)) * invk;
        o1[3] += ((s0.w + s1.w) + (s2.w + s3.w)) * invk;
    }
    if (!do_edges) return;

    // phase 3: edge pass A — count new in-degrees (reads ORIGINAL esrc/edst, no writes)
    int e0 = b * EPG_;
    for (int e = e0 + t; e < e0 + EPG_; e += 1024) {
        if (emask[e]) {
            int ns = rmap[esrc[e] - b * n];
            int nd = rmap[edst[e] - b * n];
            if (ns >= 0 && nd >= 0) atomicAdd(&cnt_s[nd], 1);
        }
    }
    __syncthreads();

    // phase 4: scan degrees over k entries -> offsets (global), cursor (LDS)
    int v = (t < k) ? cnt_s[t] : 0;
    oi_s[t] = v;
    __syncthreads();
    for (int off = 1; off < 1024; off <<= 1) {
        int tv = (t >= off) ? oi_s[t - off] : 0;
        __syncthreads();
        oi_s[t] += tv;
        __syncthreads();
    }
    int excl = oi_s[t] - v;
    if (t < k) {
        counts[b * k + t] = v;
        offsets[b * k + t] = e0 + excl;
        cnt_s[t] = excl;                 // becomes fill cursor (local)
    }
    __syncthreads();

    // phase 5: edge pass B — remap + write + fill adj (reads original, writes final)
    for (int e = e0 + t; e < e0 + EPG_; e += 1024) {
        if (emask[e]) {
            int ns = rmap[esrc[e] - b * n];
            int nd = rmap[edst[e] - b * n];
            if (ns >= 0 && nd >= 0) {
                int gs = b * k + ns;
                esrc[e] = gs;
                edst[e] = b * k + nd;
                int pos = atomicAdd(&cnt_s[nd], 1);
                adj[e0 + pos] = gs;
            } else {
                emask[e] = 0;
            }
        }
    }
}

// ---------------- host-side ----------------

extern "C" void kernel_launch(void* const* d_in, const int* in_sizes, int n_in,
                              void* d_out, int out_size, void* d_ws, size_t ws_size,
                              hipStream_t stream) {
    const float* x   = (const float*)d_in[0];
    const int*   ei  = (const int*)d_in[1];
    const float* W1l = (const float*)d_in[3];
    const float* b1  = (const float*)d_in[4];
    const float* W1r = (const float*)d_in[5];
    const float* p1  = (const float*)d_in[6];
    const float* W2l = (const float*)d_in[7];
    const float* b2  = (const float*)d_in[8];
    const float* W2r = (const float*)d_in[9];
    const float* p2  = (const float*)d_in[10];
    const float* W3l = (const float*)d_in[11];
    const float* b3  = (const float*)d_in[12];
    const float* W3r = (const float*)d_in[13];
    const float* p3  = (const float*)d_in[14];
    float* out = (float*)d_out;

    char* ws = (char*)d_ws;
    size_t off = 0;
    float* bufOut = (float*)(ws + off); off += (size_t)MP1_ * 1024 * 4;            // 64 MB
    ushort_t* Abig = (ushort_t*)(ws + off); off += (size_t)MP2_ * 4096 * 2;        // 109 MB
    ushort_t* Wb1 = (ushort_t*)(ws + off); off += (size_t)1024 * 2048 * 2;         // 4 MB
    ushort_t* Wb2 = (ushort_t*)(ws + off); off += (size_t)1024 * 4096 * 2;         // 8 MB
    ushort_t* Wb3 = (ushort_t*)(ws + off); off += (size_t)1024 * 4096 * 2;         // 8 MB
    float* sp = (float*)(ws + off); off += (size_t)16 * SPROWS_ * 4;               // 1 MB
    char* misc = ws + off;
    int*   counts = (int*)(misc + 0 * 65536);
    int*   offsets= (int*)(misc + 1 * 65536);
    int*   cursor = (int*)(misc + 2 * 65536);
    int*   old_idx= (int*)(misc + 3 * 65536);
    float* vals   = (float*)(misc + 4 * 65536);
    float* pnormv = (float*)(misc + 5 * 65536);
    int*   adj    = (int*)(misc + 6 * 65536);
    int*   esrc   = (int*)(misc + 6 * 65536 + 1 * 1048576);
    int*   edst   = (int*)(misc + 6 * 65536 + 2 * 1048576);
    int*   emask  = (int*)(misc + 6 * 65536 + 3 * 1048576);

    hipMemsetAsync(d_out, 0, (size_t)out_size * sizeof(float), stream);
    hipMemsetAsync(counts, 0, 65536, stream);
    pnorm3_kernel<<<3, 256, 0, stream>>>(p1, p2, p3, pnormv);
    pack_w_all<<<(524288 + 2 * 1048576) / 256, 256, 0, stream>>>(W1l, W1r, W2l, W2r, W3l, W3r,
                                                                 Wb1, Wb2, Wb3);
    init_edges_count<<<E_ / 256, 256, 0, stream>>>(ei, esrc, edst, emask, counts);
    scan_g16<<<B_, 1024, 0, stream>>>(counts, offsets, cursor, NP_);
    fill_kernel<<<E_ / 256, 256, 0, stream>>>(esrc, edst, emask, cursor, adj);

    // ---- layer 1 (K=512, n=1024 -> k=820) ----
    agg1_k512<<<16384, 128, 0, stream>>>(x, adj, offsets, counts, Abig);
    gemm_mfma<<<(MP1_ / 128) * 8, 256, 0, stream>>>(Abig, Wb1, b1, bufOut, sp, p1, 512, MP1_ / 128);
    tail_kernel<<<B_, 1024, 0, stream>>>(sp, pnormv + 0, bufOut, out, NP_, K1_,
                                         old_idx, vals, esrc, edst, emask,
                                         counts, offsets, adj, 1);

    // ---- layer 2 (K=1024, n=820 -> k=656) ----
    hipMemsetAsync(Abig + (size_t)M2_ * 4096, 0, (size_t)(MP2_ - M2_) * 4096 * 2, stream);
    agg23_k1024<<<32 * K1_, 128, 0, stream>>>(bufOut, adj, offsets, counts, old_idx, vals, Abig, K1_);
    gemm_mfma<<<(MP2_ / 128) * 8, 256, 0, stream>>>(Abig, Wb2, b2, bufOut, sp, p2, 1024, MP2_ / 128);
    tail_kernel<<<B_, 1024, 0, stream>>>(sp, pnormv + 1, bufOut, out, K1_, K2_,
                                         old_idx, vals, esrc, edst, emask,
                                         counts, offsets, adj, 1);

    // ---- layer 3 (K=1024, n=656 -> k=525) ----
    hipMemsetAsync(Abig + (size_t)M3_ * 4096, 0, (size_t)(MP3_ - M3_) * 4096 * 2, stream);
    agg23_k1024<<<32 * K2_, 128, 0, stream>>>(bufOut, adj, offsets, counts, old_idx, vals, Abig, K2_);
    gemm_mfma<<<(MP3_ / 128) * 8, 256, 0, stream>>>(Abig, Wb3, b3, bufOut, sp, p3, 1024, MP3_ / 128);
    tail_kernel<<<B_, 1024, 0, stream>>>(sp, pnormv + 2, bufOut, out, K2_, K3_,
                                         old_idx, vals, esrc, edst, emask,
                                         counts, offsets, adj, 0);
}

// Round 8
// 873.687 us; speedup vs baseline: 1.3562x; 1.1927x over previous
//
#include <hip/hip_runtime.h>
#include <math.h>

// Problem constants (fixed by reference)
#define B_    16
#define NP_   1024
#define FEAT_ 512
#define H_    1024
#define E_    262144          // B*NP*DEG
#define EPG_  16384           // edges per graph (edge list is graph-sorted)
#define K1_   820             // ceil(0.8*1024)
#define K2_   656             // ceil(0.8*820)
#define K3_   525             // ceil(0.8*656)
#define M1_   16384           // B*NP
#define M2_   13120           // B*K1
#define M3_   10496           // B*K2
// padded row counts: panels (Mp/128) divisible by 8 for XCD-local mapping
#define MP1_  16384           // 128 panels
#define MP2_  13312           // 104 panels
#define MP3_  11264           // 88 panels
#define SPROWS_ 16384         // scoresPart row stride

typedef unsigned short ushort_t;
typedef __bf16 bf16x8 __attribute__((ext_vector_type(8)));
typedef float f32x4 __attribute__((ext_vector_type(4)));

// ---- bf16 split helpers (RNE) ----
__device__ inline ushort_t f2bf(float f) {
    unsigned u = __float_as_uint(f);
    u += 0x7FFF + ((u >> 16) & 1);
    return (ushort_t)(u >> 16);
}
__device__ inline float bf2f(ushort_t h) {
    return __uint_as_float(((unsigned)h) << 16);
}
__device__ inline void split1(float v, ushort_t& hi, ushort_t& lo) {
    hi = f2bf(v);
    lo = f2bf(v - bf2f(hi));
}

__device__ inline void gll16(const void* g, void* l) {
    __builtin_amdgcn_global_load_lds((__attribute__((address_space(1))) void*)g,
                                     (__attribute__((address_space(3))) void*)l, 16, 0, 0);
}

// ---------------- prep: pnorms (blocks 0-2) + weight packing (blocks 3+) ----------------

__global__ __launch_bounds__(256) void prep_kernel(const float* __restrict__ p1,
                                                   const float* __restrict__ p2,
                                                   const float* __restrict__ p3,
                                                   float* __restrict__ pnout,
                                                   const float* __restrict__ W1l, const float* __restrict__ W1r,
                                                   const float* __restrict__ W2l, const float* __restrict__ W2r,
                                                   const float* __restrict__ W3l, const float* __restrict__ W3r,
                                                   ushort_t* __restrict__ Wb1, ushort_t* __restrict__ Wb2,
                                                   ushort_t* __restrict__ Wb3) {
    if (blockIdx.x < 3) {
        const float* p = blockIdx.x == 0 ? p1 : (blockIdx.x == 1 ? p2 : p3);
        __shared__ float red[256];
        float a = 0.f;
        for (int i = threadIdx.x; i < 1024; i += 256) { float v = p[i]; a += v * v; }
        red[threadIdx.x] = a;
        __syncthreads();
        for (int s = 128; s > 0; s >>= 1) {
            if (threadIdx.x < s) red[threadIdx.x] += red[threadIdx.x + s];
            __syncthreads();
        }
        if (threadIdx.x == 0) pnout[blockIdx.x] = sqrtf(red[0]);
        return;
    }
    int idx = (blockIdx.x - 3) * 256 + threadIdx.x;   // [0, 512K + 1M + 1M)
    const float *Wl, *Wr; ushort_t* Wbig; int K;
    if (idx < 524288) { Wl = W1l; Wr = W1r; Wbig = Wb1; K = 512; }
    else if (idx < 524288 + 1048576) { idx -= 524288; Wl = W2l; Wr = W2r; Wbig = Wb2; K = 1024; }
    else { idx -= 524288 + 1048576; Wl = W3l; Wr = W3r; Wbig = Wb3; K = 1024; }
    int n = idx / K;
    int k = idx - n * K;
    ushort_t* row = Wbig + (size_t)n * (4 * K);
    float a = Wl[idx];
    ushort_t ah = f2bf(a);
    row[k] = ah;
    row[K + k] = f2bf(a - bf2f(ah));
    float b = Wr[idx];
    ushort_t bh = f2bf(b);
    row[2 * K + k] = bh;
    row[3 * K + k] = f2bf(b - bf2f(bh));
}

// ---------------- csr0: per-graph count + scan + fill for layer 1 (reads ei) ----------------

__global__ __launch_bounds__(1024) void csr0_kernel(const int* __restrict__ ei,
                                                    int* __restrict__ counts,
                                                    int* __restrict__ offsets,
                                                    int* __restrict__ adj) {
    __shared__ int cnt[1024];
    __shared__ int scanb[1024];
    int b = blockIdx.x, t = threadIdx.x;
    int e0 = b * EPG_;
    cnt[t] = 0;
    __syncthreads();
    for (int e = e0 + t; e < e0 + EPG_; e += 1024)
        atomicAdd(&cnt[ei[E_ + e] - b * NP_], 1);
    __syncthreads();
    int v = cnt[t];
    scanb[t] = v;
    __syncthreads();
    for (int off = 1; off < 1024; off <<= 1) {
        int tv = (t >= off) ? scanb[t - off] : 0;
        __syncthreads();
        scanb[t] += tv;
        __syncthreads();
    }
    int excl = scanb[t] - v;
    counts[b * NP_ + t] = v;
    offsets[b * NP_ + t] = e0 + excl;
    cnt[t] = excl;                     // becomes cursor
    __syncthreads();
    for (int e = e0 + t; e < e0 + EPG_; e += 1024) {
        int s = ei[e];
        int dloc = ei[E_ + e] - b * NP_;
        int pos = atomicAdd(&cnt[dloc], 1);
        adj[e0 + pos] = s;
    }
}

// ---------------- aggregation + pack (col-split halves, XCD-pinned) ----------------
// Abig row (4K cols bf16): [agg_hi(K) | agg_lo(K) | cur_hi(K) | cur_lo(K)]

// Layer 1: source = x (K=512). 128 thr: 2 nodes x 64 float4 cols (one half).
__global__ __launch_bounds__(128) void agg1_k512(const float* __restrict__ x,
                                                 const int* __restrict__ adj,
                                                 const int* __restrict__ offsets,
                                                 const int* __restrict__ counts,
                                                 ushort_t* __restrict__ Abig) {
    int gid = blockIdx.x;
    int xcd = gid & 7;
    int u = gid >> 3;
    int half = u & 1;
    int pi = u >> 1;
    int gsel = (pi >= 512) ? 1 : 0;
    int g = xcd + (gsel << 3);
    int node = g * 1024 + (pi - (gsel << 9)) * 2 + (threadIdx.x >> 6);
    int c = threadIdx.x & 63;
    int col4 = half * 64 + c;
    int start = offsets[node], cnt = counts[node];
    float d = fmaxf((float)cnt, 1.0f);
    const float4* xb = (const float4*)x;
    float ax = 0.f, ay = 0.f, az = 0.f, aw = 0.f;
    int j = 0;
    for (; j + 8 <= cnt; j += 8) {
        int si[8];
#pragma unroll
        for (int q = 0; q < 8; ++q) si[q] = adj[start + j + q];
        float4 vv[8];
#pragma unroll
        for (int q = 0; q < 8; ++q) vv[q] = xb[(size_t)si[q] * 128 + col4];
#pragma unroll
        for (int q = 0; q < 8; ++q) {
            ax += vv[q].x; ay += vv[q].y; az += vv[q].z; aw += vv[q].w;
        }
    }
    for (; j + 4 <= cnt; j += 4) {
        int s0 = adj[start + j + 0], s1 = adj[start + j + 1];
        int s2 = adj[start + j + 2], s3 = adj[start + j + 3];
        float4 v0 = xb[(size_t)s0 * 128 + col4];
        float4 v1 = xb[(size_t)s1 * 128 + col4];
        float4 v2 = xb[(size_t)s2 * 128 + col4];
        float4 v3 = xb[(size_t)s3 * 128 + col4];
        ax += (v0.x + v1.x) + (v2.x + v3.x);
        ay += (v0.y + v1.y) + (v2.y + v3.y);
        az += (v0.z + v1.z) + (v2.z + v3.z);
        aw += (v0.w + v1.w) + (v2.w + v3.w);
    }
    for (; j < cnt; ++j) {
        float4 v = xb[(size_t)adj[start + j] * 128 + col4];
        ax += v.x; ay += v.y; az += v.z; aw += v.w;
    }
    float inv = 1.0f / d;
    float4 cv = xb[(size_t)node * 128 + col4];
    ushort_t* row = Abig + (size_t)node * 2048;
    int f = col4 * 4;
    ushort4 mh, ml, ch, cl;
    split1(ax * inv, mh.x, ml.x); split1(ay * inv, mh.y, ml.y);
    split1(az * inv, mh.z, ml.z); split1(aw * inv, mh.w, ml.w);
    split1(cv.x, ch.x, cl.x); split1(cv.y, ch.y, cl.y);
    split1(cv.z, ch.z, cl.z); split1(cv.w, ch.w, cl.w);
    *(ushort4*)&row[f]        = mh;
    *(ushort4*)&row[512 + f]  = ml;
    *(ushort4*)&row[1024 + f] = ch;
    *(ushort4*)&row[1536 + f] = cl;
}

// Layers 2/3: source = gated prev-layer h via (old_idx, vals). K=1024.
template<int LAYER>
__global__ __launch_bounds__(128) void agg23_k1024(const float* __restrict__ h,
                                                   const int* __restrict__ adj,
                                                   const int* __restrict__ offsets,
                                                   const int* __restrict__ counts,
                                                   const int* __restrict__ old_idx,
                                                   const float* __restrict__ vals,
                                                   ushort_t* __restrict__ Abig,
                                                   int n_per) {
    int gid = blockIdx.x;
    int xcd = gid & 7;
    int u = gid >> 3;
    int half = u & 1;
    int nl = u >> 1;
    int gsel = (nl >= n_per) ? 1 : 0;
    int g = xcd + (gsel << 3);
    int node = g * n_per + nl - gsel * n_per;
    int c = threadIdx.x;
    int col4 = half * 128 + c;
    int start = offsets[node], cnt = counts[node];
    float d = fmaxf((float)cnt, 1.0f);
    const float4* hb = (const float4*)h;
    float ax = 0.f, ay = 0.f, az = 0.f, aw = 0.f;
    int j = 0;
    for (; j + 8 <= cnt; j += 8) {
        int si[8];
#pragma unroll
        for (int q = 0; q < 8; ++q) si[q] = adj[start + j + q];
        int oi[8]; float wi[8];
#pragma unroll
        for (int q = 0; q < 8; ++q) { oi[q] = old_idx[si[q]]; wi[q] = vals[si[q]]; }
        float4 vv[8];
#pragma unroll
        for (int q = 0; q < 8; ++q) vv[q] = hb[(size_t)oi[q] * 256 + col4];
#pragma unroll
        for (int q = 0; q < 8; ++q) {
            ax += wi[q] * vv[q].x; ay += wi[q] * vv[q].y;
            az += wi[q] * vv[q].z; aw += wi[q] * vv[q].w;
        }
    }
    for (; j + 4 <= cnt; j += 4) {
        int s0 = adj[start + j + 0], s1 = adj[start + j + 1];
        int s2 = adj[start + j + 2], s3 = adj[start + j + 3];
        int o0 = old_idx[s0], o1 = old_idx[s1], o2 = old_idx[s2], o3 = old_idx[s3];
        float w0 = vals[s0], w1 = vals[s1], w2 = vals[s2], w3 = vals[s3];
        float4 v0 = hb[(size_t)o0 * 256 + col4];
        float4 v1 = hb[(size_t)o1 * 256 + col4];
        float4 v2 = hb[(size_t)o2 * 256 + col4];
        float4 v3 = hb[(size_t)o3 * 256 + col4];
        ax += (w0 * v0.x + w1 * v1.x) + (w2 * v2.x + w3 * v3.x);
        ay += (w0 * v0.y + w1 * v1.y) + (w2 * v2.y + w3 * v3.y);
        az += (w0 * v0.z + w1 * v1.z) + (w2 * v2.z + w3 * v3.z);
        aw += (w0 * v0.w + w1 * v1.w) + (w2 * v2.w + w3 * v3.w);
    }
    for (; j < cnt; ++j) {
        int s = adj[start + j];
        int o = old_idx[s];
        float w = vals[s];
        float4 v = hb[(size_t)o * 256 + col4];
        ax += w * v.x; ay += w * v.y; az += w * v.z; aw += w * v.w;
    }
    float inv = 1.0f / d;
    int on = old_idx[node];
    float vn = vals[node];
    float4 cv = hb[(size_t)on * 256 + col4];
    cv.x *= vn; cv.y *= vn; cv.z *= vn; cv.w *= vn;
    ushort_t* row = Abig + (size_t)node * 4096;
    int f = col4 * 4;
    ushort4 mh, ml, ch, cl;
    split1(ax * inv, mh.x, ml.x); split1(ay * inv, mh.y, ml.y);
    split1(az * inv, mh.z, ml.z); split1(aw * inv, mh.w, ml.w);
    split1(cv.x, ch.x, cl.x); split1(cv.y, ch.y, cl.y);
    split1(cv.z, ch.z, cl.z); split1(cv.w, ch.w, cl.w);
    *(ushort4*)&row[f]        = mh;
    *(ushort4*)&row[1024 + f] = ml;
    *(ushort4*)&row[2048 + f] = ch;
    *(ushort4*)&row[3072 + f] = cl;
}

// ---------------- MFMA GEMM, XCD-local panels + partial-score epilogue ----------------

template<int LAYER>
__global__ __launch_bounds__(256) void gemm_mfma(const ushort_t* __restrict__ Ab,
                                                 const ushort_t* __restrict__ Wb,
                                                 const float* __restrict__ bias,
                                                 float* __restrict__ C,
                                                 float* __restrict__ sp,
                                                 const float* __restrict__ pvec,
                                                 int K, int npanels) {
    __shared__ ushort_t lA0[4096];
    __shared__ ushort_t lA1[4096];
    __shared__ ushort_t lB0[4096];
    __shared__ ushort_t lB1[4096];
    const int LD = 4 * K;
    int tid = threadIdx.x;
    int lane = tid & 63;
    int w = tid >> 6;
    int wr = (w >> 1) * 64, wc = (w & 1) * 64;

    int gid = blockIdx.x;
    int xcd = gid & 7;
    int idx = gid >> 3;
    int panel = xcd * (npanels >> 3) + (idx >> 3);
    int cb = idx & 7;
    int m0 = panel * 128, n0 = cb * 128;

    int srow = tid >> 2;
    int gq = (tid & 3) ^ ((tid >> 2) & 3) ^ ((tid >> 4) & 3);
    const ushort_t* Ag = Ab + (size_t)(m0 + srow) * LD + gq * 8;
    const ushort_t* Bg = Wb + (size_t)(n0 + srow) * LD + gq * 8;
    ushort_t* lA0p = &lA0[tid * 8];
    ushort_t* lA1p = &lA1[tid * 8];
    ushort_t* lB0p = &lB0[tid * 8];
    ushort_t* lB1p = &lB1[tid * 8];
    const size_t rstep = (size_t)64 * LD;

    int qsw = (lane >> 4) ^ (lane & 3) ^ ((lane >> 2) & 3);
    int aidx = (wr + (lane & 15)) * 32 + qsw * 8;
    int bidx = (wc + (lane & 15)) * 32 + qsw * 8;

    f32x4 acc[4][4];
#pragma unroll
    for (int i = 0; i < 4; ++i)
#pragma unroll
        for (int j = 0; j < 4; ++j) acc[i][j] = (f32x4){0.f, 0.f, 0.f, 0.f};

    for (int ss = 0; ss < 2; ++ss) {
        const ushort_t* Ah = Ag + ss * 2 * K;
        const ushort_t* Bh = Bg + ss * 2 * K;
        for (int kk = 0; kk < K; kk += 32) {
            __syncthreads();
            gll16(Ah + kk, lA0p);
            gll16(Ah + kk + rstep, lA0p + 2048);
            gll16(Ah + K + kk, lA1p);
            gll16(Ah + K + kk + rstep, lA1p + 2048);
            gll16(Bh + kk, lB0p);
            gll16(Bh + kk + rstep, lB0p + 2048);
            gll16(Bh + K + kk, lB1p);
            gll16(Bh + K + kk + rstep, lB1p + 2048);
            __syncthreads();
            bf16x8 a0[4], a1[4], b0[4], b1[4];
#pragma unroll
            for (int i = 0; i < 4; ++i) a0[i] = *(const bf16x8*)&lA0[aidx + i * 512];
#pragma unroll
            for (int j = 0; j < 4; ++j) b0[j] = *(const bf16x8*)&lB0[bidx + j * 512];
#pragma unroll
            for (int i = 0; i < 4; ++i)
#pragma unroll
                for (int j = 0; j < 4; ++j)
                    acc[i][j] = __builtin_amdgcn_mfma_f32_16x16x32_bf16(a0[i], b0[j], acc[i][j], 0, 0, 0);
#pragma unroll
            for (int i = 0; i < 4; ++i) a1[i] = *(const bf16x8*)&lA1[aidx + i * 512];
#pragma unroll
            for (int i = 0; i < 4; ++i)
#pragma unroll
                for (int j = 0; j < 4; ++j)
                    acc[i][j] = __builtin_amdgcn_mfma_f32_16x16x32_bf16(a1[i], b0[j], acc[i][j], 0, 0, 0);
#pragma unroll
            for (int j = 0; j < 4; ++j) b1[j] = *(const bf16x8*)&lB1[bidx + j * 512];
#pragma unroll
            for (int i = 0; i < 4; ++i)
#pragma unroll
                for (int j = 0; j < 4; ++j)
                    acc[i][j] = __builtin_amdgcn_mfma_f32_16x16x32_bf16(a0[i], b1[j], acc[i][j], 0, 0, 0);
        }
    }

    float bj[4], pj[4];
#pragma unroll
    for (int j = 0; j < 4; ++j) {
        int col = n0 + wc + j * 16 + (lane & 15);
        bj[j] = bias[col];
        pj[j] = pvec[col];
    }
    int slot = cb * 2 + (wc >> 6);
#pragma unroll
    for (int i = 0; i < 4; ++i) {
        int row0 = m0 + wr + i * 16 + (lane >> 4) * 4;
        float sacc[4] = {0.f, 0.f, 0.f, 0.f};
#pragma unroll
        for (int j = 0; j < 4; ++j) {
            int col = n0 + wc + j * 16 + (lane & 15);
#pragma unroll
            for (int r = 0; r < 4; ++r) {
                float v = acc[i][j][r] + bj[j];
                v = v > 0.f ? v : 0.f;
                C[(size_t)(row0 + r) * 1024 + col] = v;
                sacc[r] += v * pj[j];
            }
        }
#pragma unroll
        for (int r = 0; r < 4; ++r) {
            float sv_ = sacc[r];
            sv_ += __shfl_xor(sv_, 1);
            sv_ += __shfl_xor(sv_, 2);
            sv_ += __shfl_xor(sv_, 4);
            sv_ += __shfl_xor(sv_, 8);
            if ((lane & 15) == 0) sp[slot * SPROWS_ + row0 + r] = sv_;
        }
    }
}

// ---------------- tail v2: 9 blocks/graph ----------------
// roles 0-7: rank-select (redundant) + readout of a 32-float4-col slice.
// role 8:    rank-select + old_idx/vals write + edge remap + CSR rebuild.
// Edges graph-sorted: graph b owns [b*EPG, (b+1)*EPG).

template<int FIRST>
__global__ __launch_bounds__(1024) void tail_kernel(const float* __restrict__ sp,
                                                    const float* __restrict__ pn,
                                                    const float* __restrict__ h,
                                                    float* __restrict__ out,
                                                    int n, int k,
                                                    int* __restrict__ old_idx, float* __restrict__ vals,
                                                    const int* __restrict__ ei,
                                                    int* __restrict__ esrc, int* __restrict__ edst,
                                                    int* __restrict__ emask,
                                                    int* __restrict__ counts, int* __restrict__ offsets,
                                                    int* __restrict__ adj, int do_edges) {
    __shared__ float sv[1024];
    __shared__ int   rmap[1024];
    __shared__ int   oi_s[1024];
    __shared__ float vv_s[1024];
    __shared__ float4 rmx[32][32];
    __shared__ float4 rsm[32][32];
    int b = blockIdx.x / 9, role = blockIdx.x % 9;
    int t = threadIdx.x;
    if (role == 8 && !do_edges) return;

    // phase 1: sum score partials, rank-select (stable descending top-k)
    float mine = -INFINITY;
    if (t < n) {
        int base = b * n + t;
        float s0 = 0.f;
#pragma unroll
        for (int c = 0; c < 16; ++c) s0 += sp[c * SPROWS_ + base];
        mine = s0;
    }
    sv[t] = mine;
    __syncthreads();
    int rank = 0;
#pragma unroll 4
    for (int j = 0; j < 1024; ++j) {
        float o = sv[j];
        rank += (o > mine) || (o == mine && j < t);
    }
    bool kept = (t < n) && (rank < k);
    rmap[t] = kept ? rank : -1;
    if (kept) {
        float tv = tanhf(mine / pn[0]);
        oi_s[rank] = b * n + t;
        vv_s[rank] = tv;
        if (role == 8) {
            old_idx[b * k + rank] = b * n + t;
            vals[b * k + rank] = tv;
        }
    }
    __syncthreads();

    if (role < 8) {
        // readout slice: 32 float4 cols, 32 row-groups
        int c32 = t & 31, g = t >> 5;
        int col4 = role * 32 + c32;
        const float4* hb = (const float4*)h;
        float4 mx = {-INFINITY, -INFINITY, -INFINITY, -INFINITY};
        float4 sm = {0.f, 0.f, 0.f, 0.f};
        for (int i = g; i < k; i += 32) {
            int o = oi_s[i];
            float wgt = vv_s[i];
            float4 v = hb[(size_t)o * 256 + col4];
            v.x *= wgt; v.y *= wgt; v.z *= wgt; v.w *= wgt;
            mx.x = fmaxf(mx.x, v.x); mx.y = fmaxf(mx.y, v.y);
            mx.z = fmaxf(mx.z, v.z); mx.w = fmaxf(mx.w, v.w);
            sm.x += v.x; sm.y += v.y; sm.z += v.z; sm.w += v.w;
        }
        rmx[g][c32] = mx; rsm[g][c32] = sm;
        __syncthreads();
        for (int s = 16; s > 0; s >>= 1) {
            if (g < s) {
                float4 om = rmx[g + s][c32], os = rsm[g + s][c32];
                float4 m = rmx[g][c32], ss2 = rsm[g][c32];
                m.x = fmaxf(m.x, om.x); m.y = fmaxf(m.y, om.y);
                m.z = fmaxf(m.z, om.z); m.w = fmaxf(m.w, om.w);
                ss2.x += os.x; ss2.y += os.y; ss2.z += os.z; ss2.w += os.w;
                rmx[g][c32] = m; rsm[g][c32] = ss2;
            }
            __syncthreads();
        }
        if (g == 0) {
            float4 m = rmx[0][c32], ss2 = rsm[0][c32];
            float invk = 1.0f / (float)k;
            float* o0 = out + (size_t)b * 2048 + col4 * 4;
            o0[0] += m.x; o0[1] += m.y; o0[2] += m.z; o0[3] += m.w;
            float* o1 = o0 + 1024;
            o1[0] += ss2.x * invk; o1[1] += ss2.y * invk;
            o1[2] += ss2.z * invk; o1[3] += ss2.w * invk;
        }
        return;
    }

    // role 8: edge phases. Reuse oi_s as scan buffer, sv as counter storage (int via cast).
    __shared__ int cnt_s[1024];
    cnt_s[t] = 0;
    __syncthreads();
    int e0 = b * EPG_;
    // pass A: count new in-degrees
    for (int e = e0 + t; e < e0 + EPG_; e += 1024) {
        int ms = FIRST ? 1 : emask[e];
        if (ms) {
            int s = FIRST ? ei[e] : esrc[e];
            int dd = FIRST ? ei[E_ + e] : edst[e];
            int ns = rmap[s - b * n];
            int nd = rmap[dd - b * n];
            if (ns >= 0 && nd >= 0) atomicAdd(&cnt_s[nd], 1);
        }
    }
    __syncthreads();
    // scan over k
    int v = (t < k) ? cnt_s[t] : 0;
    oi_s[t] = v;
    __syncthreads();
    for (int off = 1; off < 1024; off <<= 1) {
        int tv = (t >= off) ? oi_s[t - off] : 0;
        __syncthreads();
        oi_s[t] += tv;
        __syncthreads();
    }
    int excl = oi_s[t] - v;
    if (t < k) {
        counts[b * k + t] = v;
        offsets[b * k + t] = e0 + excl;
        cnt_s[t] = excl;               // becomes fill cursor
    }
    __syncthreads();
    // pass B: remap + write final edges + fill adj
    for (int e = e0 + t; e < e0 + EPG_; e += 1024) {
        int ms = FIRST ? 1 : emask[e];
        if (ms) {
            int s = FIRST ? ei[e] : esrc[e];
            int dd = FIRST ? ei[E_ + e] : edst[e];
            int ns = rmap[s - b * n];
            int nd = rmap[dd - b * n];
            if (ns >= 0 && nd >= 0) {
                int gs = b * k + ns;
                esrc[e] = gs;
                edst[e] = b * k + nd;
                if (FIRST) emask[e] = 1;
                int pos = atomicAdd(&cnt_s[nd], 1);
                adj[e0 + pos] = gs;
            } else {
                emask[e] = 0;
            }
        } else if (FIRST) {
            emask[e] = 0;
        }
    }
}

// ---------------- host-side ----------------

extern "C" void kernel_launch(void* const* d_in, const int* in_sizes, int n_in,
                              void* d_out, int out_size, void* d_ws, size_t ws_size,
                              hipStream_t stream) {
    const float* x   = (const float*)d_in[0];
    const int*   ei  = (const int*)d_in[1];
    const float* W1l = (const float*)d_in[3];
    const float* b1  = (const float*)d_in[4];
    const float* W1r = (const float*)d_in[5];
    const float* p1  = (const float*)d_in[6];
    const float* W2l = (const float*)d_in[7];
    const float* b2  = (const float*)d_in[8];
    const float* W2r = (const float*)d_in[9];
    const float* p2  = (const float*)d_in[10];
    const float* W3l = (const float*)d_in[11];
    const float* b3  = (const float*)d_in[12];
    const float* W3r = (const float*)d_in[13];
    const float* p3  = (const float*)d_in[14];
    float* out = (float*)d_out;

    char* ws = (char*)d_ws;
    size_t off = 0;
    float* bufOut = (float*)(ws + off); off += (size_t)MP1_ * 1024 * 4;            // 64 MB
    ushort_t* Abig = (ushort_t*)(ws + off); off += (size_t)MP2_ * 4096 * 2;        // 109 MB
    ushort_t* Wb1 = (ushort_t*)(ws + off); off += (size_t)1024 * 2048 * 2;         // 4 MB
    ushort_t* Wb2 = (ushort_t*)(ws + off); off += (size_t)1024 * 4096 * 2;         // 8 MB
    ushort_t* Wb3 = (ushort_t*)(ws + off); off += (size_t)1024 * 4096 * 2;         // 8 MB
    float* sp = (float*)(ws + off); off += (size_t)16 * SPROWS_ * 4;               // 1 MB
    char* misc = ws + off;
    int*   counts = (int*)(misc + 0 * 65536);
    int*   offsets= (int*)(misc + 1 * 65536);
    int*   old_idx= (int*)(misc + 2 * 65536);
    float* vals   = (float*)(misc + 3 * 65536);
    float* pnormv = (float*)(misc + 4 * 65536);
    int*   adj    = (int*)(misc + 5 * 65536);
    int*   esrc   = (int*)(misc + 5 * 65536 + 1 * 1048576);
    int*   edst   = (int*)(misc + 5 * 65536 + 2 * 1048576);
    int*   emask  = (int*)(misc + 5 * 65536 + 3 * 1048576);

    hipMemsetAsync(d_out, 0, (size_t)out_size * sizeof(float), stream);
    prep_kernel<<<3 + (524288 + 2 * 1048576) / 256, 256, 0, stream>>>(
        p1, p2, p3, pnormv, W1l, W1r, W2l, W2r, W3l, W3r, Wb1, Wb2, Wb3);
    csr0_kernel<<<B_, 1024, 0, stream>>>(ei, counts, offsets, adj);

    // ---- layer 1 (K=512, n=1024 -> k=820) ----
    agg1_k512<<<16384, 128, 0, stream>>>(x, adj, offsets, counts, Abig);
    gemm_mfma<1><<<(MP1_ / 128) * 8, 256, 0, stream>>>(Abig, Wb1, b1, bufOut, sp, p1, 512, MP1_ / 128);
    tail_kernel<1><<<B_ * 9, 1024, 0, stream>>>(sp, pnormv + 0, bufOut, out, NP_, K1_,
                                                old_idx, vals, ei, esrc, edst, emask,
                                                counts, offsets, adj, 1);

    // ---- layer 2 (K=1024, n=820 -> k=656) ----
    hipMemsetAsync(Abig + (size_t)M2_ * 4096, 0, (size_t)(MP2_ - M2_) * 4096 * 2, stream);
    agg23_k1024<2><<<32 * K1_, 128, 0, stream>>>(bufOut, adj, offsets, counts, old_idx, vals, Abig, K1_);
    gemm_mfma<2><<<(MP2_ / 128) * 8, 256, 0, stream>>>(Abig, Wb2, b2, bufOut, sp, p2, 1024, MP2_ / 128);
    tail_kernel<0><<<B_ * 9, 1024, 0, stream>>>(sp, pnormv + 1, bufOut, out, K1_, K2_,
                                                old_idx, vals, ei, esrc, edst, emask,
                                                counts, offsets, adj, 1);

    // ---- layer 3 (K=1024, n=656 -> k=525) ----
    hipMemsetAsync(Abig + (size_t)M3_ * 4096, 0, (size_t)(MP3_ - M3_) * 4096 * 2, stream);
    agg23_k1024<3><<<32 * K2_, 128, 0, stream>>>(bufOut, adj, offsets, counts, old_idx, vals, Abig, K2_);
    gemm_mfma<3><<<(MP3_ / 128) * 8, 256, 0, stream>>>(Abig, Wb3, b3, bufOut, sp, p3, 1024, MP3_ / 128);
    tail_kernel<0><<<B_ * 9, 1024, 0, stream>>>(sp, pnormv + 2, bufOut, out, K2_, K3_,
                                                old_idx, vals, ei, esrc, edst, emask,
                                                counts, offsets, adj, 0);
}

// Round 10
// 860.428 us; speedup vs baseline: 1.3771x; 1.0154x over previous
//
#include <hip/hip_runtime.h>
#include <math.h>

// Problem constants (fixed by reference)
#define B_    16
#define NP_   1024
#define FEAT_ 512
#define H_    1024
#define E_    262144          // B*NP*DEG
#define EPG_  16384           // edges per graph (edge list is graph-sorted)
#define K1_   820             // ceil(0.8*1024)
#define K2_   656             // ceil(0.8*820)
#define K3_   525             // ceil(0.8*656)
#define M1_   16384           // B*NP
#define M2_   13120           // B*K1
#define M3_   10496           // B*K2
// padded row counts: panels (Mp/128) divisible by 8 for XCD-local mapping
#define MP1_  16384           // 128 panels
#define MP2_  13312           // 104 panels
#define MP3_  11264           // 88 panels
#define SPROWS_ 16384         // scoresPart row stride

typedef unsigned short ushort_t;
typedef __bf16 bf16x8 __attribute__((ext_vector_type(8)));
typedef float f32x4 __attribute__((ext_vector_type(4)));

// ---- bf16 split helpers (RNE) ----
__device__ inline ushort_t f2bf(float f) {
    unsigned u = __float_as_uint(f);
    u += 0x7FFF + ((u >> 16) & 1);
    return (ushort_t)(u >> 16);
}
__device__ inline float bf2f(ushort_t h) {
    return __uint_as_float(((unsigned)h) << 16);
}
__device__ inline void split1(float v, ushort_t& hi, ushort_t& lo) {
    hi = f2bf(v);
    lo = f2bf(v - bf2f(hi));
}

__device__ inline void gll16(const void* g, void* l) {
    __builtin_amdgcn_global_load_lds((__attribute__((address_space(1))) void*)g,
                                     (__attribute__((address_space(3))) void*)l, 16, 0, 0);
}

// ---------------- prep2: csr0 (blocks 0-15) + pnorms (16-18) + weight pack (19+) ----------------

__global__ __launch_bounds__(1024) void prep2_kernel(const int* __restrict__ ei,
                                                     int* __restrict__ counts,
                                                     int* __restrict__ offsets,
                                                     int* __restrict__ adj,
                                                     const float* __restrict__ p1,
                                                     const float* __restrict__ p2,
                                                     const float* __restrict__ p3,
                                                     float* __restrict__ pnout,
                                                     const float* __restrict__ W1l, const float* __restrict__ W1r,
                                                     const float* __restrict__ W2l, const float* __restrict__ W2r,
                                                     const float* __restrict__ W3l, const float* __restrict__ W3r,
                                                     ushort_t* __restrict__ Wb1, ushort_t* __restrict__ Wb2,
                                                     ushort_t* __restrict__ Wb3) {
    int t = threadIdx.x;
    if (blockIdx.x < 16) {
        // per-graph CSR build (count + scan + fill), graph b owns [b*EPG, (b+1)*EPG)
        __shared__ int cnt[1024];
        __shared__ int scanb[1024];
        int b = blockIdx.x;
        int e0 = b * EPG_;
        cnt[t] = 0;
        __syncthreads();
        for (int e = e0 + t; e < e0 + EPG_; e += 1024)
            atomicAdd(&cnt[ei[E_ + e] - b * NP_], 1);
        __syncthreads();
        int v = cnt[t];
        scanb[t] = v;
        __syncthreads();
        for (int off = 1; off < 1024; off <<= 1) {
            int tv = (t >= off) ? scanb[t - off] : 0;
            __syncthreads();
            scanb[t] += tv;
            __syncthreads();
        }
        int excl = scanb[t] - v;
        counts[b * NP_ + t] = v;
        offsets[b * NP_ + t] = e0 + excl;
        cnt[t] = excl;                     // becomes cursor
        __syncthreads();
        for (int e = e0 + t; e < e0 + EPG_; e += 1024) {
            int s = ei[e];
            int dloc = ei[E_ + e] - b * NP_;
            int pos = atomicAdd(&cnt[dloc], 1);
            adj[e0 + pos] = s;
        }
        return;
    }
    if (blockIdx.x < 19) {
        const float* p = blockIdx.x == 16 ? p1 : (blockIdx.x == 17 ? p2 : p3);
        __shared__ float red[1024];
        float a = p[t];
        red[t] = a * a;
        __syncthreads();
        for (int s = 512; s > 0; s >>= 1) {
            if (t < s) red[t] += red[t + s];
            __syncthreads();
        }
        if (t == 0) pnout[blockIdx.x - 16] = sqrtf(red[0]);
        return;
    }
    int idx = (blockIdx.x - 19) * 1024 + t;     // [0, 512K + 1M + 1M)
    if (idx >= 524288 + 1048576 + 1048576) return;
    const float *Wl, *Wr; ushort_t* Wbig; int K;
    if (idx < 524288) { Wl = W1l; Wr = W1r; Wbig = Wb1; K = 512; }
    else if (idx < 524288 + 1048576) { idx -= 524288; Wl = W2l; Wr = W2r; Wbig = Wb2; K = 1024; }
    else { idx -= 524288 + 1048576; Wl = W3l; Wr = W3r; Wbig = Wb3; K = 1024; }
    int n = idx / K;
    int k = idx - n * K;
    ushort_t* row = Wbig + (size_t)n * (4 * K);
    float a = Wl[idx];
    ushort_t ah = f2bf(a);
    row[k] = ah;
    row[K + k] = f2bf(a - bf2f(ah));
    float b = Wr[idx];
    ushort_t bh = f2bf(b);
    row[2 * K + k] = bh;
    row[3 * K + k] = f2bf(b - bf2f(bh));
}

// ---------------- aggregation + pack (col-split halves, XCD-pinned) ----------------
// Abig row (4K cols bf16): [agg_hi(K) | agg_lo(K) | cur_hi(K) | cur_lo(K)]

// Layer 1: source = x (K=512). 128 thr: 2 nodes x 64 float4 cols (one half).
__global__ __launch_bounds__(128) void agg1_k512(const float* __restrict__ x,
                                                 const int* __restrict__ adj,
                                                 const int* __restrict__ offsets,
                                                 const int* __restrict__ counts,
                                                 ushort_t* __restrict__ Abig) {
    int gid = blockIdx.x;
    int xcd = gid & 7;
    int u = gid >> 3;
    int half = u & 1;
    int pi = u >> 1;
    int gsel = (pi >= 512) ? 1 : 0;
    int g = xcd + (gsel << 3);
    int node = g * 1024 + (pi - (gsel << 9)) * 2 + (threadIdx.x >> 6);
    int c = threadIdx.x & 63;
    int col4 = half * 64 + c;
    int start = offsets[node], cnt = counts[node];
    float d = fmaxf((float)cnt, 1.0f);
    const float4* xb = (const float4*)x;
    float ax = 0.f, ay = 0.f, az = 0.f, aw = 0.f;
    int j = 0;
    for (; j + 8 <= cnt; j += 8) {
        int si[8];
#pragma unroll
        for (int q = 0; q < 8; ++q) si[q] = adj[start + j + q];
        float4 vv[8];
#pragma unroll
        for (int q = 0; q < 8; ++q) vv[q] = xb[(size_t)si[q] * 128 + col4];
#pragma unroll
        for (int q = 0; q < 8; ++q) {
            ax += vv[q].x; ay += vv[q].y; az += vv[q].z; aw += vv[q].w;
        }
    }
    for (; j + 4 <= cnt; j += 4) {
        int s0 = adj[start + j + 0], s1 = adj[start + j + 1];
        int s2 = adj[start + j + 2], s3 = adj[start + j + 3];
        float4 v0 = xb[(size_t)s0 * 128 + col4];
        float4 v1 = xb[(size_t)s1 * 128 + col4];
        float4 v2 = xb[(size_t)s2 * 128 + col4];
        float4 v3 = xb[(size_t)s3 * 128 + col4];
        ax += (v0.x + v1.x) + (v2.x + v3.x);
        ay += (v0.y + v1.y) + (v2.y + v3.y);
        az += (v0.z + v1.z) + (v2.z + v3.z);
        aw += (v0.w + v1.w) + (v2.w + v3.w);
    }
    for (; j < cnt; ++j) {
        float4 v = xb[(size_t)adj[start + j] * 128 + col4];
        ax += v.x; ay += v.y; az += v.z; aw += v.w;
    }
    float inv = 1.0f / d;
    float4 cv = xb[(size_t)node * 128 + col4];
    ushort_t* row = Abig + (size_t)node * 2048;
    int f = col4 * 4;
    ushort4 mh, ml, ch, cl;
    split1(ax * inv, mh.x, ml.x); split1(ay * inv, mh.y, ml.y);
    split1(az * inv, mh.z, ml.z); split1(aw * inv, mh.w, ml.w);
    split1(cv.x, ch.x, cl.x); split1(cv.y, ch.y, cl.y);
    split1(cv.z, ch.z, cl.z); split1(cv.w, ch.w, cl.w);
    *(ushort4*)&row[f]        = mh;
    *(ushort4*)&row[512 + f]  = ml;
    *(ushort4*)&row[1024 + f] = ch;
    *(ushort4*)&row[1536 + f] = cl;
}

// Layers 2/3: source = gated prev-layer h via (old_idx, vals). K=1024.
// Blocks [0, 32*n_per): aggregation. Blocks >= 32*n_per: zero one padded Abig row each.
template<int LAYER>
__global__ __launch_bounds__(128) void agg23_k1024(const float* __restrict__ h,
                                                   const int* __restrict__ adj,
                                                   const int* __restrict__ offsets,
                                                   const int* __restrict__ counts,
                                                   const int* __restrict__ old_idx,
                                                   const float* __restrict__ vals,
                                                   ushort_t* __restrict__ Abig,
                                                   int n_per, int M, int npad) {
    int gid = blockIdx.x;
    if (gid >= 32 * n_per) {
        // pad-zero row M + r (r in [0, npad))
        int r = gid - 32 * n_per;
        if (r < npad) {
            uint4* row = (uint4*)(Abig + (size_t)(M + r) * 4096);   // 512 uint4
#pragma unroll
            for (int q = 0; q < 4; ++q) row[threadIdx.x + q * 128] = (uint4){0, 0, 0, 0};
        }
        return;
    }
    int xcd = gid & 7;
    int u = gid >> 3;
    int half = u & 1;
    int nl = u >> 1;
    int gsel = (nl >= n_per) ? 1 : 0;
    int g = xcd + (gsel << 3);
    int node = g * n_per + nl - gsel * n_per;
    int c = threadIdx.x;
    int col4 = half * 128 + c;
    int start = offsets[node], cnt = counts[node];
    float d = fmaxf((float)cnt, 1.0f);
    const float4* hb = (const float4*)h;
    float ax = 0.f, ay = 0.f, az = 0.f, aw = 0.f;
    int j = 0;
    for (; j + 8 <= cnt; j += 8) {
        int si[8];
#pragma unroll
        for (int q = 0; q < 8; ++q) si[q] = adj[start + j + q];
        int oi[8]; float wi[8];
#pragma unroll
        for (int q = 0; q < 8; ++q) { oi[q] = old_idx[si[q]]; wi[q] = vals[si[q]]; }
        float4 vv[8];
#pragma unroll
        for (int q = 0; q < 8; ++q) vv[q] = hb[(size_t)oi[q] * 256 + col4];
#pragma unroll
        for (int q = 0; q < 8; ++q) {
            ax += wi[q] * vv[q].x; ay += wi[q] * vv[q].y;
            az += wi[q] * vv[q].z; aw += wi[q] * vv[q].w;
        }
    }
    for (; j + 4 <= cnt; j += 4) {
        int s0 = adj[start + j + 0], s1 = adj[start + j + 1];
        int s2 = adj[start + j + 2], s3 = adj[start + j + 3];
        int o0 = old_idx[s0], o1 = old_idx[s1], o2 = old_idx[s2], o3 = old_idx[s3];
        float w0 = vals[s0], w1 = vals[s1], w2 = vals[s2], w3 = vals[s3];
        float4 v0 = hb[(size_t)o0 * 256 + col4];
        float4 v1 = hb[(size_t)o1 * 256 + col4];
        float4 v2 = hb[(size_t)o2 * 256 + col4];
        float4 v3 = hb[(size_t)o3 * 256 + col4];
        ax += (w0 * v0.x + w1 * v1.x) + (w2 * v2.x + w3 * v3.x);
        ay += (w0 * v0.y + w1 * v1.y) + (w2 * v2.y + w3 * v3.y);
        az += (w0 * v0.z + w1 * v1.z) + (w2 * v2.z + w3 * v3.z);
        aw += (w0 * v0.w + w1 * v1.w) + (w2 * v2.w + w3 * v3.w);
    }
    for (; j < cnt; ++j) {
        int s = adj[start + j];
        int o = old_idx[s];
        float w = vals[s];
        float4 v = hb[(size_t)o * 256 + col4];
        ax += w * v.x; ay += w * v.y; az += w * v.z; aw += w * v.w;
    }
    float inv = 1.0f / d;
    int on = old_idx[node];
    float vn = vals[node];
    float4 cv = hb[(size_t)on * 256 + col4];
    cv.x *= vn; cv.y *= vn; cv.z *= vn; cv.w *= vn;
    ushort_t* row = Abig + (size_t)node * 4096;
    int f = col4 * 4;
    ushort4 mh, ml, ch, cl;
    split1(ax * inv, mh.x, ml.x); split1(ay * inv, mh.y, ml.y);
    split1(az * inv, mh.z, ml.z); split1(aw * inv, mh.w, ml.w);
    split1(cv.x, ch.x, cl.x); split1(cv.y, ch.y, cl.y);
    split1(cv.z, ch.z, cl.z); split1(cv.w, ch.w, cl.w);
    *(ushort4*)&row[f]        = mh;
    *(ushort4*)&row[1024 + f] = ml;
    *(ushort4*)&row[2048 + f] = ch;
    *(ushort4*)&row[3072 + f] = cl;
}

// ---------------- MFMA GEMM, XCD-local panels + partial-score epilogue ----------------

template<int LAYER>
__global__ __launch_bounds__(256) void gemm_mfma(const ushort_t* __restrict__ Ab,
                                                 const ushort_t* __restrict__ Wb,
                                                 const float* __restrict__ bias,
                                                 float* __restrict__ C,
                                                 float* __restrict__ sp,
                                                 const float* __restrict__ pvec,
                                                 int K, int npanels) {
    __shared__ ushort_t lA0[4096];
    __shared__ ushort_t lA1[4096];
    __shared__ ushort_t lB0[4096];
    __shared__ ushort_t lB1[4096];
    const int LD = 4 * K;
    int tid = threadIdx.x;
    int lane = tid & 63;
    int w = tid >> 6;
    int wr = (w >> 1) * 64, wc = (w & 1) * 64;

    int gid = blockIdx.x;
    int xcd = gid & 7;
    int idx = gid >> 3;
    int panel = xcd * (npanels >> 3) + (idx >> 3);
    int cb = idx & 7;
    int m0 = panel * 128, n0 = cb * 128;

    int srow = tid >> 2;
    int gq = (tid & 3) ^ ((tid >> 2) & 3) ^ ((tid >> 4) & 3);
    const ushort_t* Ag = Ab + (size_t)(m0 + srow) * LD + gq * 8;
    const ushort_t* Bg = Wb + (size_t)(n0 + srow) * LD + gq * 8;
    ushort_t* lA0p = &lA0[tid * 8];
    ushort_t* lA1p = &lA1[tid * 8];
    ushort_t* lB0p = &lB0[tid * 8];
    ushort_t* lB1p = &lB1[tid * 8];
    const size_t rstep = (size_t)64 * LD;

    int qsw = (lane >> 4) ^ (lane & 3) ^ ((lane >> 2) & 3);
    int aidx = (wr + (lane & 15)) * 32 + qsw * 8;
    int bidx = (wc + (lane & 15)) * 32 + qsw * 8;

    f32x4 acc[4][4];
#pragma unroll
    for (int i = 0; i < 4; ++i)
#pragma unroll
        for (int j = 0; j < 4; ++j) acc[i][j] = (f32x4){0.f, 0.f, 0.f, 0.f};

    for (int ss = 0; ss < 2; ++ss) {
        const ushort_t* Ah = Ag + ss * 2 * K;
        const ushort_t* Bh = Bg + ss * 2 * K;
        for (int kk = 0; kk < K; kk += 32) {
            __syncthreads();
            gll16(Ah + kk, lA0p);
            gll16(Ah + kk + rstep, lA0p + 2048);
            gll16(Ah + K + kk, lA1p);
            gll16(Ah + K + kk + rstep, lA1p + 2048);
            gll16(Bh + kk, lB0p);
            gll16(Bh + kk + rstep, lB0p + 2048);
            gll16(Bh + K + kk, lB1p);
            gll16(Bh + K + kk + rstep, lB1p + 2048);
            __syncthreads();
            bf16x8 a0[4], a1[4], b0[4], b1[4];
#pragma unroll
            for (int i = 0; i < 4; ++i) a0[i] = *(const bf16x8*)&lA0[aidx + i * 512];
#pragma unroll
            for (int j = 0; j < 4; ++j) b0[j] = *(const bf16x8*)&lB0[bidx + j * 512];
#pragma unroll
            for (int i = 0; i < 4; ++i)
#pragma unroll
                for (int j = 0; j < 4; ++j)
                    acc[i][j] = __builtin_amdgcn_mfma_f32_16x16x32_bf16(a0[i], b0[j], acc[i][j], 0, 0, 0);
#pragma unroll
            for (int i = 0; i < 4; ++i) a1[i] = *(const bf16x8*)&lA1[aidx + i * 512];
#pragma unroll
            for (int i = 0; i < 4; ++i)
#pragma unroll
                for (int j = 0; j < 4; ++j)
                    acc[i][j] = __builtin_amdgcn_mfma_f32_16x16x32_bf16(a1[i], b0[j], acc[i][j], 0, 0, 0);
#pragma unroll
            for (int j = 0; j < 4; ++j) b1[j] = *(const bf16x8*)&lB1[bidx + j * 512];
#pragma unroll
            for (int i = 0; i < 4; ++i)
#pragma unroll
                for (int j = 0; j < 4; ++j)
                    acc[i][j] = __builtin_amdgcn_mfma_f32_16x16x32_bf16(a0[i], b1[j], acc[i][j], 0, 0, 0);
        }
    }

    float bj[4], pj[4];
#pragma unroll
    for (int j = 0; j < 4; ++j) {
        int col = n0 + wc + j * 16 + (lane & 15);
        bj[j] = bias[col];
        pj[j] = pvec[col];
    }
    int slot = cb * 2 + (wc >> 6);
#pragma unroll
    for (int i = 0; i < 4; ++i) {
        int row0 = m0 + wr + i * 16 + (lane >> 4) * 4;
        float sacc[4] = {0.f, 0.f, 0.f, 0.f};
#pragma unroll
        for (int j = 0; j < 4; ++j) {
            int col = n0 + wc + j * 16 + (lane & 15);
#pragma unroll
            for (int r = 0; r < 4; ++r) {
                float v = acc[i][j][r] + bj[j];
                v = v > 0.f ? v : 0.f;
                C[(size_t)(row0 + r) * 1024 + col] = v;
                sacc[r] += v * pj[j];
            }
        }
#pragma unroll
        for (int r = 0; r < 4; ++r) {
            float sv_ = sacc[r];
            sv_ += __shfl_xor(sv_, 1);
            sv_ += __shfl_xor(sv_, 2);
            sv_ += __shfl_xor(sv_, 4);
            sv_ += __shfl_xor(sv_, 8);
            if ((lane & 15) == 0) sp[slot * SPROWS_ + row0 + r] = sv_;
        }
    }
}

// ---------------- tail: 9 blocks/graph (R8-proven, 1024 threads) ----------------
// roles 0-7: rank-select (redundant) + readout of a 32-float4-col slice.
// role 8:    rank-select + old_idx/vals write + edge remap + CSR rebuild.
// FIRST also selects '=' vs '+=' on the out write (removes d_out memset).

template<int FIRST>
__global__ __launch_bounds__(1024) void tail_kernel(const float* __restrict__ sp,
                                                    const float* __restrict__ pn,
                                                    const float* __restrict__ h,
                                                    float* __restrict__ out,
                                                    int n, int k,
                                                    int* __restrict__ old_idx, float* __restrict__ vals,
                                                    const int* __restrict__ ei,
                                                    int* __restrict__ esrc, int* __restrict__ edst,
                                                    int* __restrict__ emask,
                                                    int* __restrict__ counts, int* __restrict__ offsets,
                                                    int* __restrict__ adj, int do_edges) {
    __shared__ float sv[1024];
    __shared__ int   rmap[1024];
    __shared__ int   oi_s[1024];
    __shared__ float vv_s[1024];
    __shared__ float4 rmx[32][32];
    __shared__ float4 rsm[32][32];
    int b = blockIdx.x / 9, role = blockIdx.x % 9;
    int t = threadIdx.x;
    if (role == 8 && !do_edges) return;

    // phase 1: sum score partials, rank-select (stable descending top-k)
    float mine = -INFINITY;
    if (t < n) {
        int base = b * n + t;
        float s0 = 0.f;
#pragma unroll
        for (int c = 0; c < 16; ++c) s0 += sp[c * SPROWS_ + base];
        mine = s0;
    }
    sv[t] = mine;
    __syncthreads();
    int rank = 0;
#pragma unroll 4
    for (int j = 0; j < 1024; ++j) {
        float o = sv[j];
        rank += (o > mine) || (o == mine && j < t);
    }
    bool kept = (t < n) && (rank < k);
    rmap[t] = kept ? rank : -1;
    if (kept) {
        float tv = tanhf(mine / pn[0]);
        oi_s[rank] = b * n + t;
        vv_s[rank] = tv;
        if (role == 8) {
            old_idx[b * k + rank] = b * n + t;
            vals[b * k + rank] = tv;
        }
    }
    __syncthreads();

    if (role < 8) {
        // readout slice: 32 float4 cols, 32 row-groups
        int c32 = t & 31, g = t >> 5;
        int col4 = role * 32 + c32;
        const float4* hb = (const float4*)h;
        float4 mx = {-INFINITY, -INFINITY, -INFINITY, -INFINITY};
        float4 sm = {0.f, 0.f, 0.f, 0.f};
        for (int i = g; i < k; i += 32) {
            int o = oi_s[i];
            float wgt = vv_s[i];
            float4 v = hb[(size_t)o * 256 + col4];
            v.x *= wgt; v.y *= wgt; v.z *= wgt; v.w *= wgt;
            mx.x = fmaxf(mx.x, v.x); mx.y = fmaxf(mx.y, v.y);
            mx.z = fmaxf(mx.z, v.z); mx.w = fmaxf(mx.w, v.w);
            sm.x += v.x; sm.y += v.y; sm.z += v.z; sm.w += v.w;
        }
        rmx[g][c32] = mx; rsm[g][c32] = sm;
        __syncthreads();
        for (int s = 16; s > 0; s >>= 1) {
            if (g < s) {
                float4 om = rmx[g + s][c32], os = rsm[g + s][c32];
                float4 m = rmx[g][c32], ss2 = rsm[g][c32];
                m.x = fmaxf(m.x, om.x); m.y = fmaxf(m.y, om.y);
                m.z = fmaxf(m.z, om.z); m.w = fmaxf(m.w, om.w);
                ss2.x += os.x; ss2.y += os.y; ss2.z += os.z; ss2.w += os.w;
                rmx[g][c32] = m; rsm[g][c32] = ss2;
            }
            __syncthreads();
        }
        if (g == 0) {
            float4 m = rmx[0][c32], ss2 = rsm[0][c32];
            float invk = 1.0f / (float)k;
            float* o0 = out + (size_t)b * 2048 + col4 * 4;
            float* o1 = o0 + 1024;
            if (FIRST) {
                o0[0] = m.x; o0[1] = m.y; o0[2] = m.z; o0[3] = m.w;
                o1[0] = ss2.x * invk; o1[1] = ss2.y * invk;
                o1[2] = ss2.z * invk; o1[3] = ss2.w * invk;
            } else {
                o0[0] += m.x; o0[1] += m.y; o0[2] += m.z; o0[3] += m.w;
                o1[0] += ss2.x * invk; o1[1] += ss2.y * invk;
                o1[2] += ss2.z * invk; o1[3] += ss2.w * invk;
            }
        }
        return;
    }

    // role 8: edge phases
    __shared__ int cnt_s[1024];
    cnt_s[t] = 0;
    __syncthreads();
    int e0 = b * EPG_;
    // pass A: count new in-degrees
    for (int e = e0 + t; e < e0 + EPG_; e += 1024) {
        int ms = FIRST ? 1 : emask[e];
        if (ms) {
            int s = FIRST ? ei[e] : esrc[e];
            int dd = FIRST ? ei[E_ + e] : edst[e];
            int ns = rmap[s - b * n];
            int nd = rmap[dd - b * n];
            if (ns >= 0 && nd >= 0) atomicAdd(&cnt_s[nd], 1);
        }
    }
    __syncthreads();
    // scan over k
    int v = (t < k) ? cnt_s[t] : 0;
    oi_s[t] = v;
    __syncthreads();
    for (int off = 1; off < 1024; off <<= 1) {
        int tv = (t >= off) ? oi_s[t - off] : 0;
        __syncthreads();
        oi_s[t] += tv;
        __syncthreads();
    }
    int excl = oi_s[t] - v;
    if (t < k) {
        counts[b * k + t] = v;
        offsets[b * k + t] = e0 + excl;
        cnt_s[t] = excl;               // becomes fill cursor
    }
    __syncthreads();
    // pass B: remap + write final edges + fill adj
    for (int e = e0 + t; e < e0 + EPG_; e += 1024) {
        int ms = FIRST ? 1 : emask[e];
        if (ms) {
            int s = FIRST ? ei[e] : esrc[e];
            int dd = FIRST ? ei[E_ + e] : edst[e];
            int ns = rmap[s - b * n];
            int nd = rmap[dd - b * n];
            if (ns >= 0 && nd >= 0) {
                int gs = b * k + ns;
                esrc[e] = gs;
                edst[e] = b * k + nd;
                if (FIRST) emask[e] = 1;
                int pos = atomicAdd(&cnt_s[nd], 1);
                adj[e0 + pos] = gs;
            } else {
                emask[e] = 0;
            }
        } else if (FIRST) {
            emask[e] = 0;
        }
    }
}

// ---------------- host-side ----------------

extern "C" void kernel_launch(void* const* d_in, const int* in_sizes, int n_in,
                              void* d_out, int out_size, void* d_ws, size_t ws_size,
                              hipStream_t stream) {
    const float* x   = (const float*)d_in[0];
    const int*   ei  = (const int*)d_in[1];
    const float* W1l = (const float*)d_in[3];
    const float* b1  = (const float*)d_in[4];
    const float* W1r = (const float*)d_in[5];
    const float* p1  = (const float*)d_in[6];
    const float* W2l = (const float*)d_in[7];
    const float* b2  = (const float*)d_in[8];
    const float* W2r = (const float*)d_in[9];
    const float* p2  = (const float*)d_in[10];
    const float* W3l = (const float*)d_in[11];
    const float* b3  = (const float*)d_in[12];
    const float* W3r = (const float*)d_in[13];
    const float* p3  = (const float*)d_in[14];
    float* out = (float*)d_out;

    char* ws = (char*)d_ws;
    size_t off = 0;
    float* bufOut = (float*)(ws + off); off += (size_t)MP1_ * 1024 * 4;            // 64 MB
    ushort_t* Abig = (ushort_t*)(ws + off); off += (size_t)MP2_ * 4096 * 2;        // 109 MB
    ushort_t* Wb1 = (ushort_t*)(ws + off); off += (size_t)1024 * 2048 * 2;         // 4 MB
    ushort_t* Wb2 = (ushort_t*)(ws + off); off += (size_t)1024 * 4096 * 2;         // 8 MB
    ushort_t* Wb3 = (ushort_t*)(ws + off); off += (size_t)1024 * 4096 * 2;         // 8 MB
    float* sp = (float*)(ws + off); off += (size_t)16 * SPROWS_ * 4;               // 1 MB
    char* misc = ws + off;
    int*   counts = (int*)(misc + 0 * 65536);
    int*   offsets= (int*)(misc + 1 * 65536);
    int*   old_idx= (int*)(misc + 2 * 65536);
    float* vals   = (float*)(misc + 3 * 65536);
    float* pnormv = (float*)(misc + 4 * 65536);
    int*   adj    = (int*)(misc + 5 * 65536);
    int*   esrc   = (int*)(misc + 5 * 65536 + 1 * 1048576);
    int*   edst   = (int*)(misc + 5 * 65536 + 2 * 1048576);
    int*   emask  = (int*)(misc + 5 * 65536 + 3 * 1048576);

    // prep2: csr0 (16 blocks) + pnorms (3) + weight packing (2560)
    prep2_kernel<<<19 + (524288 + 2 * 1048576) / 1024, 1024, 0, stream>>>(
        ei, counts, offsets, adj, p1, p2, p3, pnormv,
        W1l, W1r, W2l, W2r, W3l, W3r, Wb1, Wb2, Wb3);

    // ---- layer 1 (K=512, n=1024 -> k=820) ----
    agg1_k512<<<16384, 128, 0, stream>>>(x, adj, offsets, counts, Abig);
    gemm_mfma<1><<<(MP1_ / 128) * 8, 256, 0, stream>>>(Abig, Wb1, b1, bufOut, sp, p1, 512, MP1_ / 128);
    tail_kernel<1><<<B_ * 9, 1024, 0, stream>>>(sp, pnormv + 0, bufOut, out, NP_, K1_,
                                                old_idx, vals, ei, esrc, edst, emask,
                                                counts, offsets, adj, 1);

    // ---- layer 2 (K=1024, n=820 -> k=656); pad rows zeroed by extra agg blocks ----
    agg23_k1024<2><<<32 * K1_ + (MP2_ - M2_), 128, 0, stream>>>(
        bufOut, adj, offsets, counts, old_idx, vals, Abig, K1_, M2_, MP2_ - M2_);
    gemm_mfma<2><<<(MP2_ / 128) * 8, 256, 0, stream>>>(Abig, Wb2, b2, bufOut, sp, p2, 1024, MP2_ / 128);
    tail_kernel<0><<<B_ * 9, 1024, 0, stream>>>(sp, pnormv + 1, bufOut, out, K1_, K2_,
                                                old_idx, vals, ei, esrc, edst, emask,
                                                counts, offsets, adj, 1);

    // ---- layer 3 (K=1024, n=656 -> k=525) ----
    agg23_k1024<3><<<32 * K2_ + (MP3_ - M3_), 128, 0, stream>>>(
        bufOut, adj, offsets, counts, old_idx, vals, Abig, K2_, M3_, MP3_ - M3_);
    gemm_mfma<3><<<(MP3_ / 128) * 8, 256, 0, stream>>>(Abig, Wb3, b3, bufOut, sp, p3, 1024, MP3_ / 128);
    tail_kernel<0><<<B_ * 9, 1024, 0, stream>>>(sp, pnormv + 2, bufOut, out, K2_, K3_,
                                                old_idx, vals, ei, esrc, edst, emask,
                                                counts, offsets, adj, 0);
}